// Round 13
// baseline (1478.883 us; speedup 1.0000x reference)
//
#include <hip/hip_runtime.h>

// ---------------------------------------------------------------------------
// CSBrainAlign: spectral conv -> 4 mamba blocks (fwd chain then bwd chain,
// sequential) -> fuse@6 positions -> band/pos/hemi -> attn pool -> MLP.
// EXTERNAL dtype: float32 (per reference), int32 perm. Internal acts bf16,
// residual H fp32, fuse path fp32, output fp32.
// R6: scan lane=(d,n) remap. R7: GEMM family -> MFMA bf16.
// R9 scan v6 (best): 4 n/thread, dt phase, zl staged. R10: mm XCD grids,
// LDS spec1. R11 inline-dt REVERTED.
// R13: scan LDS diet (dtl/ybuf bf16: 74->42 KB, 2->3 blocks/CU);
//      prep kernels merged (k_prep); smagg+lnm -> k_smln; g1+f3 -> k_gf.
// ---------------------------------------------------------------------------

typedef unsigned short u16;
using bf16x8 = __attribute__((ext_vector_type(8))) short;
using f32x4  = __attribute__((ext_vector_type(4))) float;

#define TT    384      // sequence length N*P
#define BCn   128      // B*C
#define TOKn  49152    // BCn*TT (one chain)
#define CH3   64       // scan chunk (steps)
#define NCH3  (TT/CH3) // 6 chunks

__device__ __forceinline__ float b2f(u16 u) {
  return __uint_as_float(((unsigned)u) << 16);
}
__device__ __forceinline__ u16 f2b(float f) {
  unsigned u = __float_as_uint(f);
  u += 0x7fffu + ((u >> 16) & 1u);   // RNE
  return (u16)(u >> 16);
}
__device__ __forceinline__ float gelu_t(float x) {
  float u2 = 1.5957691216057308f * (x + 0.044715f * x * x * x);
  float e = __expf(u2);
  float th = 1.f - 2.f / (e + 1.f);
  return 0.5f * x * (1.f + th);
}
__device__ __forceinline__ float silu_f(float x) { return x / (1.f + __expf(-x)); }
__device__ __forceinline__ float softplus_f(float x) {
  return fmaxf(x, 0.f) + log1pf(__expf(-fabsf(x)));
}

__device__ __forceinline__ float block_sum(float v, float* sb) {
  #pragma unroll
  for (int m = 32; m; m >>= 1) v += __shfl_xor(v, m);
  int lane = threadIdx.x & 63, wid = threadIdx.x >> 6;
  if (lane == 0) sb[wid] = v;
  __syncthreads();
  float tot = sb[0] + sb[1] + sb[2] + sb[3];
  __syncthreads();
  return tot;
}

// ---------------------------------------------------------------------------
// MFMA GEMM: out[tok][n] = X[tok][0:KT] @ W[0:KT][n],  X bf16, WT bf16 [n][k].
// grid = (tokTiles, nTiles): same-A blocks land on one XCD.
// EPI: 0 spectral -> H f32 (+bias; rev!=0 time-reversed)
//      1 W_in     -> XZ bf16 (stride 512)
//      2 W_x      -> XDBL f32 (stride 40, store n<40)
//      3 W_out    -> H += acc + bias
// ---------------------------------------------------------------------------
template <int EPI, int KT>
__global__ __launch_bounds__(256) void k_mm(
    const u16* __restrict__ X, const u16* __restrict__ WT,
    const float* __restrict__ bias, int Nw, int rev,
    float* __restrict__ o0, u16* __restrict__ ob0) {
  constexpr int AK = KT + 8;          // row pad
  __shared__ u16 As[64 * AK];
  __shared__ u16 Bs[64 * AK];
  const int tid = threadIdx.x;
  const int tok0 = blockIdx.x * 64;
  const int n0 = blockIdx.y * 64;

  constexpr int VPR = KT / 8;
  constexpr int ITER = 64 * VPR / 256;
  #pragma unroll
  for (int j = 0; j < ITER; ++j) {
    int idx = tid + j * 256;
    int row = idx / VPR, vec = idx % VPR;
    *reinterpret_cast<uint4*>(&As[row * AK + vec * 8]) =
        *reinterpret_cast<const uint4*>(&X[(size_t)(tok0 + row) * KT + vec * 8]);
    *reinterpret_cast<uint4*>(&Bs[row * AK + vec * 8]) =
        *reinterpret_cast<const uint4*>(&WT[(size_t)(n0 + row) * KT + vec * 8]);
  }
  __syncthreads();

  const int w = tid >> 6, lane = tid & 63;
  const int wm = (w & 1) * 32, wn = (w >> 1) * 32;
  const int lrow = lane & 15, quad = lane >> 4;
  f32x4 acc[2][2] = {};
  #pragma unroll
  for (int ks = 0; ks < KT / 32; ++ks) {
    int koff = ks * 32 + quad * 8;
    bf16x8 a0 = *reinterpret_cast<const bf16x8*>(&As[(wm + lrow) * AK + koff]);
    bf16x8 a1 = *reinterpret_cast<const bf16x8*>(&As[(wm + 16 + lrow) * AK + koff]);
    bf16x8 b0 = *reinterpret_cast<const bf16x8*>(&Bs[(wn + lrow) * AK + koff]);
    bf16x8 b1 = *reinterpret_cast<const bf16x8*>(&Bs[(wn + 16 + lrow) * AK + koff]);
    acc[0][0] = __builtin_amdgcn_mfma_f32_16x16x32_bf16(a0, b0, acc[0][0], 0, 0, 0);
    acc[0][1] = __builtin_amdgcn_mfma_f32_16x16x32_bf16(a0, b1, acc[0][1], 0, 0, 0);
    acc[1][0] = __builtin_amdgcn_mfma_f32_16x16x32_bf16(a1, b0, acc[1][0], 0, 0, 0);
    acc[1][1] = __builtin_amdgcn_mfma_f32_16x16x32_bf16(a1, b1, acc[1][1], 0, 0, 0);
  }

  #pragma unroll
  for (int mi = 0; mi < 2; ++mi)
    #pragma unroll
    for (int ni = 0; ni < 2; ++ni)
      #pragma unroll
      for (int r = 0; r < 4; ++r) {
        int tok = tok0 + wm + mi * 16 + quad * 4 + r;
        int n = n0 + wn + ni * 16 + lrow;
        float v = acc[mi][ni][r];
        if (EPI == 0) {
          v += bias[n];
          int bc = tok / TT, t = tok % TT;
          int tok2 = rev ? (bc * TT + (TT - 1 - t)) : tok;
          o0[(size_t)tok2 * 128 + n] = v;
        } else if (EPI == 1) {
          ob0[(size_t)tok * 512 + n] = f2b(v);
        } else if (EPI == 2) {
          if (n < 40) o0[(size_t)tok * 40 + n] = v;
        } else if (EPI == 3) {
          v += bias[n];
          o0[(size_t)tok * 128 + n] += v;
        }
      }
  (void)Nw;
}

// ---- merged weight prep: f32 -> bf16, transposed to [n][k] ----
// grid 1856: [0,1024) tin | [1024,1536) tout | [1536,1792) tx | [1792,1856) tsp
__global__ __launch_bounds__(256) void k_prep(const float* __restrict__ Win,
                                              const float* __restrict__ Wout,
                                              const float* __restrict__ Wx,
                                              const float* __restrict__ Wsp,
                                              u16* __restrict__ WTin,
                                              u16* __restrict__ WTout,
                                              u16* __restrict__ WTx,
                                              u16* __restrict__ WTsp) {
  int bid = blockIdx.x;
  int tid = threadIdx.x;
  if (bid < 1024) {
    int i = bid * 256 + tid;                 // 4*512*128
    int blk = i >> 16, r = i & 65535;
    int n = r >> 7, k = r & 127;
    WTin[i] = f2b(Win[blk * 65536 + k * 512 + n]);
  } else if (bid < 1536) {
    int i = (bid - 1024) * 256 + tid;        // 4*128*256
    int blk = i >> 15, r = i & 32767;
    int n = r >> 8, k = r & 255;
    WTout[i] = f2b(Wout[blk * 32768 + k * 128 + n]);
  } else if (bid < 1792) {
    int i = (bid - 1536) * 256 + tid;        // 4*64*256
    int blk = i >> 14, r = i & 16383;
    int n = r >> 8, k = r & 255;
    WTx[i] = (n < 40) ? f2b(Wx[blk * 10240 + k * 40 + n]) : 0;
  } else {
    int i = (bid - 1792) * 256 + tid;        // 128*128
    WTsp[i] = f2b(Wsp[i]);
  }
}

// spectral conv7 (pad 3) + bias + gelu -> F bf16 [token][c]
__global__ __launch_bounds__(256) void k_spec1(const float* __restrict__ x,
                                               const float* __restrict__ w1,
                                               const float* __restrict__ b1,
                                               u16* __restrict__ F) {
  __shared__ float xs[70];
  __shared__ float wsh[128 * 7];
  __shared__ float bs[128];
  int bc = blockIdx.x / 6, tile = blockIdx.x % 6;
  int tid = threadIdx.x;
  for (int i = tid; i < 896; i += 256) wsh[i] = w1[i];
  if (tid < 128) bs[tid] = b1[tid];
  int t0 = tile * 64;
  if (tid < 70) {
    int t = t0 - 3 + tid;
    xs[tid] = (t >= 0 && t < TT) ? x[(size_t)bc * TT + t] : 0.f;
  }
  __syncthreads();
  #pragma unroll
  for (int k = 0; k < 32; ++k) {
    int idx = tid + k * 256;
    int tl = idx >> 7, c = idx & 127;
    const float* wr = &wsh[c * 7];
    float acc = bs[c];
    #pragma unroll
    for (int j = 0; j < 7; ++j) acc += xs[tl + j] * wr[j];
    F[((size_t)(bc * TT + t0 + tl)) * 128 + c] = f2b(gelu_t(acc));
  }
}

// per-token LayerNorm over D=128: H f32 -> XLN bf16 (weights pre-offset)
__global__ __launch_bounds__(256) void k_ln(const float* __restrict__ H,
                                            const float* __restrict__ gg,
                                            const float* __restrict__ bb,
                                            u16* __restrict__ XLN) {
  int tid = threadIdx.x;
  int lane = tid & 63, wid = tid >> 6;
  int token = blockIdx.x * 4 + wid;
  const float* hr = H + (size_t)token * 128;
  float a = hr[lane], b = hr[lane + 64];
  float s = a + b;
  #pragma unroll
  for (int m = 32; m; m >>= 1) s += __shfl_xor(s, m);
  float mean = s * (1.f / 128.f);
  float d1 = a - mean, d2 = b - mean;
  float q = d1 * d1 + d2 * d2;
  #pragma unroll
  for (int m = 32; m; m >>= 1) q += __shfl_xor(q, m);
  float rs = rsqrtf(q * (1.f / 128.f) + 1e-5f);
  XLN[(size_t)token * 128 + lane] = f2b(d1 * rs * gg[lane] + bb[lane]);
  XLN[(size_t)token * 128 + lane + 64] =
      f2b(d2 * rs * gg[lane + 64] + bb[lane + 64]);
}

// causal depthwise conv (DC=4) + silu : XZ[:, :256] -> XC (4 chan/thread)
__global__ __launch_bounds__(256) void k_conv(const u16* __restrict__ XZ,
                                              const float* __restrict__ cw,
                                              const float* __restrict__ cb,
                                              u16* __restrict__ XC) {
  int idx = blockIdx.x * 256 + threadIdx.x;   // TOKn * 64
  int d4 = idx & 63;
  int tokg = idx >> 6;
  int t = tokg % TT;
  int dbase = d4 * 4;
  const float* cwp = cw + dbase * 4;
  float wv[4][4];
  #pragma unroll
  for (int j = 0; j < 4; ++j)
    #pragma unroll
    for (int k = 0; k < 4; ++k) wv[j][k] = cwp[j * 4 + k];
  float accv[4];
  #pragma unroll
  for (int j = 0; j < 4; ++j) accv[j] = cb[dbase + j];
  #pragma unroll
  for (int k = 0; k < 4; ++k) {
    int tt = t + k - 3;
    if (tt < 0) continue;
    ushort4 xv = *reinterpret_cast<const ushort4*>(
        &XZ[(size_t)(tokg + k - 3) * 512 + dbase]);
    u16 xa[4];
    *reinterpret_cast<ushort4*>(xa) = xv;
    #pragma unroll
    for (int j = 0; j < 4; ++j) accv[j] += b2f(xa[j]) * wv[j][k];
  }
  u16 oa[4];
  #pragma unroll
  for (int j = 0; j < 4; ++j) oa[j] = f2b(silu_f(accv[j]));
  *reinterpret_cast<ushort4*>(&XC[(size_t)tokg * 256 + dbase]) =
      *reinterpret_cast<ushort4*>(oa);
}

// ---------------------------------------------------------------------------
// selective scan v6d (R13): grid = 128 bc x 4 dq, 256 threads.
// Scan phase: thread owns (d, 4 n): dl = tid>>2, ng = tid&3.
// dt phase once per d; zl staged; dtl/ybuf bf16 (LDS 42 KB -> 3 blocks/CU).
// ---------------------------------------------------------------------------
__global__ __launch_bounds__(256) void k_scan(
    const float* __restrict__ XDBL, u16* __restrict__ XC,
    const u16* __restrict__ XZ, const float* __restrict__ Wdt,
    const float* __restrict__ bdt, const float* __restrict__ Alog,
    const float* __restrict__ Dpv) {
  __shared__ float xdl[CH3 * 40];    // 10 KB
  __shared__ u16   dtl[CH3 * 64];    // 8 KB (bf16)
  __shared__ u16   xcl[CH3 * 64];    // 8 KB
  __shared__ u16   zl [CH3 * 64];    // 8 KB
  __shared__ u16   ybuf[CH3 * 64];   // 8 KB (bf16)
  const int tid = threadIdx.x;
  const int bc = blockIdx.x >> 2, dq = blockIdx.x & 3;
  const int ng = tid & 3;            // n-group (scan)
  const int dl = tid >> 2;           // d_local (scan)
  const int dcol = tid & 63;         // d_local (dt/epilogue)

  const int d_scan = dq * 64 + dl;
  float A[4];
  #pragma unroll
  for (int j = 0; j < 4; ++j)
    A[j] = -__expf(Alog[d_scan * 16 + ng * 4 + j]);
  float wdtr[8];
  #pragma unroll
  for (int j = 0; j < 8; ++j) wdtr[j] = Wdt[j * 256 + dq * 64 + dcol];
  const float bd = bdt[dq * 64 + dcol];
  const float dpar = Dpv[dq * 64 + dcol];

  const size_t base = (size_t)bc * TT;
  const float* xdg = XDBL + base * 40;
  const uint4* xcu4 = (const uint4*)XC;
  const uint4* zu4  = (const uint4*)XZ;

  float sx[10];
  uint4 scx[2], szx[2];
  auto issue_loads = [&](int c) {
    const float* p = xdg + (size_t)c * CH3 * 40;
    #pragma unroll
    for (int k = 0; k < 10; ++k) sx[k] = p[tid + k * 256];
    #pragma unroll
    for (int k = 0; k < 2; ++k) {
      int v = tid + k * 256;           // 0..511: t = v>>3, q = v&7
      int t = v >> 3, q = v & 7;
      size_t tok = base + (size_t)c * CH3 + t;
      scx[k] = xcu4[tok * 32 + dq * 8 + q];
      szx[k] = zu4[tok * 64 + 32 + dq * 8 + q];
    }
  };
  auto write_lds = [&]() {
    #pragma unroll
    for (int k = 0; k < 10; ++k) xdl[tid + k * 256] = sx[k];
    #pragma unroll
    for (int k = 0; k < 2; ++k) {
      int v = tid + k * 256;
      ((uint4*)xcl)[v] = scx[k];
      ((uint4*)zl)[v] = szx[k];
    }
  };

  issue_loads(0);
  write_lds();
  __syncthreads();

  float hc[4] = {};
  for (int c = 0; c < NCH3; ++c) {
    if (c + 1 < NCH3) issue_loads(c + 1);
    // dt phase: 16 values/thread at fixed dcol; float4 xdl reads
    #pragma unroll
    for (int k = 0; k < 16; ++k) {
      int t = (tid >> 6) + 4 * k;
      float4 x0 = *reinterpret_cast<const float4*>(&xdl[t * 40]);
      float4 x1 = *reinterpret_cast<const float4*>(&xdl[t * 40 + 4]);
      float acc = bd;
      acc += x0.x * wdtr[0] + x0.y * wdtr[1] + x0.z * wdtr[2] + x0.w * wdtr[3];
      acc += x1.x * wdtr[4] + x1.y * wdtr[5] + x1.z * wdtr[6] + x1.w * wdtr[7];
      dtl[t * 64 + dcol] = f2b(softplus_f(acc));
    }
    __syncthreads();
    // scan phase: 64 steps, 4 n per thread
    #pragma unroll 4
    for (int t = 0; t < CH3; ++t) {
      float dtv = b2f(dtl[t * 64 + dl]);
      float xcv = b2f(xcl[t * 64 + dl]);
      float4 Bv = *reinterpret_cast<const float4*>(&xdl[t * 40 + 8 + ng * 4]);
      float4 Cv = *reinterpret_cast<const float4*>(&xdl[t * 40 + 24 + ng * 4]);
      float dx = dtv * xcv;
      float e0 = __expf(A[0] * dtv);
      float e1 = __expf(A[1] * dtv);
      float e2 = __expf(A[2] * dtv);
      float e3 = __expf(A[3] * dtv);
      hc[0] = fmaf(hc[0], e0, dx * Bv.x);
      hc[1] = fmaf(hc[1], e1, dx * Bv.y);
      hc[2] = fmaf(hc[2], e2, dx * Bv.z);
      hc[3] = fmaf(hc[3], e3, dx * Bv.w);
      float yv = hc[0] * Cv.x + hc[1] * Cv.y + hc[2] * Cv.z + hc[3] * Cv.w;
      yv += __shfl_xor(yv, 1);
      yv += __shfl_xor(yv, 2);
      if (ng == 0) ybuf[t * 64 + dl] = f2b(yv);
    }
    __syncthreads();
    // epilogue: 16 values/thread at fixed dcol; coalesced store
    #pragma unroll
    for (int k = 0; k < 16; ++k) {
      int t = (tid >> 6) + 4 * k;
      int v = t * 64 + dcol;
      float y = b2f(ybuf[v]);
      float xcv = b2f(xcl[v]);
      float zz = b2f(zl[v]);
      y = (y + xcv * dpar) * silu_f(zz);
      XC[(base + (size_t)c * CH3 + t) * 256 + dq * 64 + dcol] = f2b(y);
    }
    __syncthreads();
    if (c + 1 < NCH3) {
      write_lds();
      __syncthreads();
    }
  }
}

// gather the 6 needed positions into XF[768][256] f32 (half=0 fwd,128 bwd)
__global__ __launch_bounds__(256) void k_gather(const float* __restrict__ H,
                                                float* __restrict__ XF,
                                                int half, int revpos) {
  int i = blockIdx.x * 256 + threadIdx.x;   // 768*128
  int col = i & 127, row = i >> 7;
  int bc = row / 6, u = row % 6;
  int tu = 63 + 64 * u;
  int t = revpos ? (TT - 1 - tu) : tu;
  XF[(size_t)row * 256 + half + col] = H[(size_t)(bc * TT + t) * 128 + col];
}

// fuse: FE[row][d] = XF[row][:] @ fuse_w + fuse_b   (768 rows, K=256)
__global__ __launch_bounds__(128) void k_fuse(const float* __restrict__ XF,
                                              const float* __restrict__ fw,
                                              const float* __restrict__ fb,
                                              float* __restrict__ FE) {
  int row = blockIdx.x;
  int d = threadIdx.x;
  __shared__ float rows[256];
  rows[d] = XF[(size_t)row * 256 + d];
  rows[128 + d] = XF[(size_t)row * 256 + 128 + d];
  __syncthreads();
  float acc = fb[d];
  for (int k = 0; k < 256; ++k) acc += rows[k] * fw[k * 128 + d];
  FE[(size_t)row * 128 + d] = acc;
}

// band projection + event reorder: TO[(bc*9+j)][d]
__global__ __launch_bounds__(128) void k_band(const float* __restrict__ FE,
                                              const float* __restrict__ pw,
                                              const float* __restrict__ pb,
                                              const float* __restrict__ pe,
                                              float* __restrict__ TO) {
  const int u_of[9] = {0, 1, 2, 2, 3, 4, 5, 5, 5};
  const int k_of[9] = {0, 0, 0, 1, 0, 0, 0, 1, 2};
  int bid = blockIdx.x;
  int bc = bid / 9, j = bid % 9;
  int u = u_of[j], kq = k_of[j];
  __shared__ float fs[128];
  int d = threadIdx.x;
  fs[d] = FE[(size_t)(bc * 6 + u) * 128 + d];
  __syncthreads();
  float acc = pb[kq * 128 + d] + pe[kq * 128 + d];
  const float* wp = pw + kq * 16384 + d;
  for (int c = 0; c < 128; ++c) acc += fs[c] * wp[c * 128];
  TO[(size_t)bid * 128 + d] = acc;
}

// depthwise 19x7 pos conv over (C=32, L=9) + residual -> T2 [b][c][l][d]
__global__ __launch_bounds__(256) void k_pos(const float* __restrict__ TO,
                                             const float* __restrict__ pw,
                                             const float* __restrict__ pb,
                                             float* __restrict__ T2) {
  int idx = blockIdx.x * 256 + threadIdx.x;   // 147456
  int d = idx & 127;
  int l = (idx >> 7) % 9;
  int c = (idx / 1152) & 31;
  int b = idx / 36864;
  float acc = 0.f;
  const float* wd = pw + d * 133;
  for (int i = 0; i < 19; ++i) {
    int ci = c + i - 9;
    if (ci < 0 || ci >= 32) continue;
    const float* trow = TO + (size_t)(b * 32 + ci) * 9 * 128 + d;
    #pragma unroll
    for (int jj = 0; jj < 7; ++jj) {
      int lj = l + jj - 3;
      if (lj < 0 || lj >= 9) continue;
      acc += trow[lj * 128] * wd[i * 7 + jj];
    }
  }
  T2[idx] = TO[idx] + acc + pb[d];
}

// hemisphere fusion: concat(own, permuted) @ hemi_w + hemi_b -> FL (flatf)
__global__ __launch_bounds__(128) void k_hemi(const float* __restrict__ T2,
                                              const int* __restrict__ perm,
                                              const float* __restrict__ hw,
                                              const float* __restrict__ hb,
                                              float* __restrict__ FL) {
  int bid = blockIdx.x;   // b*288 + c*9 + l
  int b = bid / 288;
  int c = (bid / 9) % 32;
  int l = bid % 9;
  int pc = perm[b * 32 + c];
  __shared__ float rows[256];
  int d = threadIdx.x;
  rows[d] = T2[((size_t)(b * 32 + c) * 9 + l) * 128 + d];
  rows[128 + d] = T2[((size_t)(b * 32 + pc) * 9 + l) * 128 + d];
  __syncthreads();
  float acc = hb[d];
  for (int k = 0; k < 256; ++k) acc += rows[k] * hw[k * 128 + d];
  FL[(size_t)(b * 32 + c) * 1152 + l * 128 + d] = acc;
}

// attention logits: LN(1152) -> @a_w1(200) -> gelu -> @a_w2 -> logit
__global__ __launch_bounds__(256) void k_attn(
    const float* __restrict__ FL, const float* __restrict__ lg,
    const float* __restrict__ lb, const float* __restrict__ w1,
    const float* __restrict__ b1, const float* __restrict__ w2,
    const float* __restrict__ ab2, float* __restrict__ LO) {
  __shared__ float xn[1152];
  __shared__ float sb[4];
  int row = blockIdx.x;
  int tid = threadIdx.x;
  const float* xr = FL + (size_t)row * 1152;
  float xl[5];
  int cnt = 0;
  float s = 0.f;
  for (int i = tid; i < 1152; i += 256) { xl[cnt] = xr[i]; s += xl[cnt]; ++cnt; }
  float tot = block_sum(s, sb);
  float mean = tot * (1.f / 1152.f);
  float q = 0.f;
  for (int k = 0; k < cnt; ++k) { float dd = xl[k] - mean; q += dd * dd; }
  float qt = block_sum(q, sb);
  float rs = rsqrtf(qt * (1.f / 1152.f) + 1e-5f);
  cnt = 0;
  for (int i = tid; i < 1152; i += 256) {
    xn[i] = (xl[cnt] - mean) * rs * lg[i] + lb[i];
    ++cnt;
  }
  __syncthreads();
  float g = 0.f;
  if (tid < 200) {
    float acc = b1[tid];
    for (int i = 0; i < 1152; ++i) acc += xn[i] * w1[i * 200 + tid];
    g = gelu_t(acc);
  }
  __syncthreads();
  if (tid < 200) xn[tid] = g;
  __syncthreads();
  float s2 = (tid < 200) ? xn[tid] * w2[tid] : 0.f;
  float t2 = block_sum(s2, sb);
  if (tid == 0) LO[row] = t2 + ab2[0];
}

// merged: softmax over C=32, weighted agg, final LN -> AGN[b][1152]
__global__ __launch_bounds__(256) void k_smln(const float* __restrict__ FL,
                                              const float* __restrict__ LO,
                                              const float* __restrict__ lg,
                                              const float* __restrict__ lb,
                                              float* __restrict__ AGN) {
  int b = blockIdx.x;
  int tid = threadIdx.x;
  __shared__ float w[32];
  __shared__ float sb[4];
  if (tid == 0) {
    float mx = -1e30f;
    for (int c = 0; c < 32; ++c) mx = fmaxf(mx, LO[b * 32 + c]);
    float sum = 0.f;
    for (int c = 0; c < 32; ++c) { float e = __expf(LO[b * 32 + c] - mx); w[c] = e; sum += e; }
    float inv = 1.f / sum;
    for (int c = 0; c < 32; ++c) w[c] *= inv;
  }
  __syncthreads();
  float xl[5];
  int cnt = 0;
  float s = 0.f;
  for (int f = tid; f < 1152; f += 256) {
    float acc = 0.f;
    for (int c = 0; c < 32; ++c) acc += FL[(size_t)(b * 32 + c) * 1152 + f] * w[c];
    xl[cnt++] = acc;
    s += acc;
  }
  float tot = block_sum(s, sb);
  float mean = tot * (1.f / 1152.f);
  float q = 0.f;
  for (int k = 0; k < cnt; ++k) { float dd = xl[k] - mean; q += dd * dd; }
  float qt = block_sum(q, sb);
  float rs = rsqrtf(qt * (1.f / 1152.f) + 1e-5f);
  cnt = 0;
  for (int f = tid; f < 1152; f += 256) {
    AGN[b * 1152 + f] = (xl[cnt] - mean) * rs * lg[f] + lb[f];
    ++cnt;
  }
}

// merged: g1 = gelu(AGN @ m_w1 + m_b1) (LDS) then out = g1 @ m_w2 + m_b2
__global__ __launch_bounds__(256) void k_gf(const float* __restrict__ AGN,
                                            const float* __restrict__ w1,
                                            const float* __restrict__ b1,
                                            const float* __restrict__ w2,
                                            const float* __restrict__ b2v,
                                            float* __restrict__ out) {
  int b = blockIdx.x;
  int tid = threadIdx.x;
  __shared__ float av[1152];
  __shared__ float gv[1024];
  for (int i = tid; i < 1152; i += 256) av[i] = AGN[b * 1152 + i];
  __syncthreads();
  #pragma unroll
  for (int k = 0; k < 4; ++k) {
    int j = tid + k * 256;
    float acc = b1[j];
    for (int i = 0; i < 1152; ++i) acc += av[i] * w1[(size_t)i * 1024 + j];
    gv[j] = gelu_t(acc);
  }
  __syncthreads();
  #pragma unroll
  for (int k = 0; k < 3; ++k) {
    int o = tid + k * 256;
    float acc = b2v[o];
    for (int i = 0; i < 1024; ++i) acc += gv[i] * w2[(size_t)i * 768 + o];
    out[b * 768 + o] = acc;
  }
}

extern "C" void kernel_launch(void* const* d_in, const int* in_sizes, int n_in,
                              void* d_out, int out_size, void* d_ws,
                              size_t ws_size, hipStream_t stream) {
  (void)in_sizes; (void)n_in; (void)out_size; (void)ws_size;
  const float* x      = (const float*)d_in[0];
  const int*   perm   = (const int*)d_in[1];
  const float* sp_w1  = (const float*)d_in[2];
  const float* sp_b1  = (const float*)d_in[3];
  const float* sp_w2  = (const float*)d_in[4];
  const float* sp_b2  = (const float*)d_in[5];
  const float* ln_g   = (const float*)d_in[6];
  const float* ln_b   = (const float*)d_in[7];
  const float* W_in   = (const float*)d_in[8];
  const float* conv_w = (const float*)d_in[9];
  const float* conv_b = (const float*)d_in[10];
  const float* W_x    = (const float*)d_in[11];
  const float* W_dt   = (const float*)d_in[12];
  const float* b_dt   = (const float*)d_in[13];
  const float* A_log  = (const float*)d_in[14];
  const float* Dp     = (const float*)d_in[15];
  const float* W_out  = (const float*)d_in[16];
  const float* b_out  = (const float*)d_in[17];
  const float* fuse_w = (const float*)d_in[18];
  const float* fuse_b = (const float*)d_in[19];
  const float* band_emb = (const float*)d_in[20];
  const float* band_pw  = (const float*)d_in[21];
  const float* band_pb  = (const float*)d_in[22];
  const float* pos_w  = (const float*)d_in[23];
  const float* pos_b  = (const float*)d_in[24];
  const float* hemi_w = (const float*)d_in[25];
  const float* hemi_b = (const float*)d_in[26];
  const float* a_ln_g = (const float*)d_in[27];
  const float* a_ln_b = (const float*)d_in[28];
  const float* a_w1   = (const float*)d_in[29];
  const float* a_b1   = (const float*)d_in[30];
  const float* a_w2   = (const float*)d_in[31];
  const float* a_b2   = (const float*)d_in[32];
  const float* m_ln_g = (const float*)d_in[33];
  const float* m_ln_b = (const float*)d_in[34];
  const float* m_w1   = (const float*)d_in[35];
  const float* m_b1   = (const float*)d_in[36];
  const float* m_w2   = (const float*)d_in[37];
  const float* m_b2   = (const float*)d_in[38];

  char* ws = (char*)d_ws;
  size_t off = 0;
  auto alloc = [&](size_t bytes) -> char* {
    char* p = ws + off;
    off += (bytes + 255) & ~(size_t)255;
    return p;
  };
  // peak ~139 MiB
  float* H    = (float*)alloc((size_t)TOKn * 128 * 4);   // 25.2M
  u16*   F    = (u16*)  alloc((size_t)TOKn * 128 * 2);   // 12.6M
  u16*   XLN  = (u16*)  alloc((size_t)TOKn * 128 * 2);   // 12.6M
  u16*   XZ   = (u16*)  alloc((size_t)TOKn * 512 * 2);   // 50.3M
  u16*   XC   = (u16*)  alloc((size_t)TOKn * 256 * 2);   // 25.2M
  float* XDBL = (float*)alloc((size_t)TOKn * 40 * 4);    // 7.9M
  u16*   WTin = (u16*)alloc(4 * 512 * 128 * 2);
  u16*   WTout= (u16*)alloc(4 * 128 * 256 * 2);
  u16*   WTx  = (u16*)alloc(4 * 64 * 256 * 2);
  u16*   WTsp = (u16*)alloc(128 * 128 * 2);
  float* XF   = (float*)alloc(768 * 256 * 4);
  float* FE   = (float*)alloc(768 * 128 * 4);
  float* TO   = (float*)alloc(1152 * 128 * 4);
  float* T2v  = (float*)alloc(147456 * 4);
  float* FL   = (float*)alloc(147456 * 4);
  float* LO   = (float*)alloc(128 * 4);
  float* AGN  = (float*)alloc(4 * 1152 * 4);

  // merged weight prep (bf16, [n][k])
  k_prep<<<dim3(1856), dim3(256), 0, stream>>>(
      W_in, W_out, W_x, sp_w2, WTin, WTout, WTx, WTsp);

  // spectral front-end
  k_spec1<<<dim3(BCn * 6), dim3(256), 0, stream>>>(x, sp_w1, sp_b1, F);

  auto mamba_round = [&](int blk) {
    k_ln<<<dim3(TOKn / 4), dim3(256), 0, stream>>>(
        H, ln_g + blk * 128, ln_b + blk * 128, XLN);
    k_mm<1, 128><<<dim3(TOKn / 64, 8), dim3(256), 0, stream>>>(
        XLN, WTin + (size_t)blk * 65536, nullptr, 512, 0, nullptr, XZ);
    k_conv<<<dim3(TOKn * 64 / 256), dim3(256), 0, stream>>>(
        XZ, conv_w + blk * 1024, conv_b + blk * 256, XC);
    k_mm<2, 256><<<dim3(TOKn / 64, 1), dim3(256), 0, stream>>>(
        XC, WTx + (size_t)blk * 16384, nullptr, 40, 0, XDBL, nullptr);
    k_scan<<<dim3(BCn * 4), dim3(256), 0, stream>>>(
        XDBL, XC, XZ, W_dt + blk * 2048, b_dt + blk * 256,
        A_log + blk * 4096, Dp + blk * 256);
    k_mm<3, 256><<<dim3(TOKn / 64, 2), dim3(256), 0, stream>>>(
        XC, WTout + (size_t)blk * 32768, b_out + blk * 128, 128, 0,
        H, nullptr);
  };

  // forward chain (blocks 0,1)
  k_mm<0, 128><<<dim3(TOKn / 64, 2), dim3(256), 0, stream>>>(
      F, WTsp, sp_b2, 128, 0, H, nullptr);
  mamba_round(0);
  mamba_round(1);
  k_gather<<<dim3(384), dim3(256), 0, stream>>>(H, XF, 0, 0);

  // backward chain (blocks 2,3) on time-reversed h
  k_mm<0, 128><<<dim3(TOKn / 64, 2), dim3(256), 0, stream>>>(
      F, WTsp, sp_b2, 128, 1, H, nullptr);
  mamba_round(2);
  mamba_round(3);
  k_gather<<<dim3(384), dim3(256), 0, stream>>>(H, XF, 128, 1);

  // tail
  k_fuse<<<dim3(768), dim3(128), 0, stream>>>(XF, fuse_w, fuse_b, FE);
  k_band<<<dim3(1152), dim3(128), 0, stream>>>(FE, band_pw, band_pb, band_emb, TO);
  k_pos<<<dim3(576), dim3(256), 0, stream>>>(TO, pos_w, pos_b, T2v);
  k_hemi<<<dim3(1152), dim3(128), 0, stream>>>(T2v, perm, hemi_w, hemi_b, FL);
  k_attn<<<dim3(128), dim3(256), 0, stream>>>(FL, a_ln_g, a_ln_b, a_w1, a_b1,
                                              a_w2, a_b2, LO);
  k_smln<<<dim3(4), dim3(256), 0, stream>>>(FL, LO, m_ln_g, m_ln_b, AGN);
  k_gf<<<dim3(4), dim3(256), 0, stream>>>(AGN, m_w1, m_b1, m_w2, m_b2,
                                          (float*)d_out);
}

// Round 14
// 1313.438 us; speedup vs baseline: 1.1260x; 1.1260x over previous
//
#include <hip/hip_runtime.h>

// ---------------------------------------------------------------------------
// CSBrainAlign: spectral conv -> 4 mamba blocks (fwd chain then bwd chain,
// sequential) -> fuse@6 positions -> band/pos/hemi -> attn pool -> MLP.
// EXTERNAL dtype: float32 (per reference), int32 perm. Internal acts bf16,
// residual H fp32, fuse path fp32, output fp32.
// R6: scan lane=(d,n) remap. R7: GEMM family -> MFMA bf16.
// R9 scan v6 (best): 4 n/thread, dt phase, zl staged. R10: mm XCD grids,
// LDS spec1. R11 inline-dt REVERTED.
// R13: scan LDS diet (dtl/ybuf bf16, 42 KB); k_prep; k_smln.
// R14: k_gf (merged MLP, 4 blocks, 265us — parallelism-starved) REVERTED
//      to k_g1 (grid 16) + k_f3 (grid 12).
// ---------------------------------------------------------------------------

typedef unsigned short u16;
using bf16x8 = __attribute__((ext_vector_type(8))) short;
using f32x4  = __attribute__((ext_vector_type(4))) float;

#define TT    384      // sequence length N*P
#define BCn   128      // B*C
#define TOKn  49152    // BCn*TT (one chain)
#define CH3   64       // scan chunk (steps)
#define NCH3  (TT/CH3) // 6 chunks

__device__ __forceinline__ float b2f(u16 u) {
  return __uint_as_float(((unsigned)u) << 16);
}
__device__ __forceinline__ u16 f2b(float f) {
  unsigned u = __float_as_uint(f);
  u += 0x7fffu + ((u >> 16) & 1u);   // RNE
  return (u16)(u >> 16);
}
__device__ __forceinline__ float gelu_t(float x) {
  float u2 = 1.5957691216057308f * (x + 0.044715f * x * x * x);
  float e = __expf(u2);
  float th = 1.f - 2.f / (e + 1.f);
  return 0.5f * x * (1.f + th);
}
__device__ __forceinline__ float silu_f(float x) { return x / (1.f + __expf(-x)); }
__device__ __forceinline__ float softplus_f(float x) {
  return fmaxf(x, 0.f) + log1pf(__expf(-fabsf(x)));
}

__device__ __forceinline__ float block_sum(float v, float* sb) {
  #pragma unroll
  for (int m = 32; m; m >>= 1) v += __shfl_xor(v, m);
  int lane = threadIdx.x & 63, wid = threadIdx.x >> 6;
  if (lane == 0) sb[wid] = v;
  __syncthreads();
  float tot = sb[0] + sb[1] + sb[2] + sb[3];
  __syncthreads();
  return tot;
}

// ---------------------------------------------------------------------------
// MFMA GEMM: out[tok][n] = X[tok][0:KT] @ W[0:KT][n],  X bf16, WT bf16 [n][k].
// grid = (tokTiles, nTiles): same-A blocks land on one XCD.
// EPI: 0 spectral -> H f32 (+bias; rev!=0 time-reversed)
//      1 W_in     -> XZ bf16 (stride 512)
//      2 W_x      -> XDBL f32 (stride 40, store n<40)
//      3 W_out    -> H += acc + bias
// ---------------------------------------------------------------------------
template <int EPI, int KT>
__global__ __launch_bounds__(256) void k_mm(
    const u16* __restrict__ X, const u16* __restrict__ WT,
    const float* __restrict__ bias, int Nw, int rev,
    float* __restrict__ o0, u16* __restrict__ ob0) {
  constexpr int AK = KT + 8;          // row pad
  __shared__ u16 As[64 * AK];
  __shared__ u16 Bs[64 * AK];
  const int tid = threadIdx.x;
  const int tok0 = blockIdx.x * 64;
  const int n0 = blockIdx.y * 64;

  constexpr int VPR = KT / 8;
  constexpr int ITER = 64 * VPR / 256;
  #pragma unroll
  for (int j = 0; j < ITER; ++j) {
    int idx = tid + j * 256;
    int row = idx / VPR, vec = idx % VPR;
    *reinterpret_cast<uint4*>(&As[row * AK + vec * 8]) =
        *reinterpret_cast<const uint4*>(&X[(size_t)(tok0 + row) * KT + vec * 8]);
    *reinterpret_cast<uint4*>(&Bs[row * AK + vec * 8]) =
        *reinterpret_cast<const uint4*>(&WT[(size_t)(n0 + row) * KT + vec * 8]);
  }
  __syncthreads();

  const int w = tid >> 6, lane = tid & 63;
  const int wm = (w & 1) * 32, wn = (w >> 1) * 32;
  const int lrow = lane & 15, quad = lane >> 4;
  f32x4 acc[2][2] = {};
  #pragma unroll
  for (int ks = 0; ks < KT / 32; ++ks) {
    int koff = ks * 32 + quad * 8;
    bf16x8 a0 = *reinterpret_cast<const bf16x8*>(&As[(wm + lrow) * AK + koff]);
    bf16x8 a1 = *reinterpret_cast<const bf16x8*>(&As[(wm + 16 + lrow) * AK + koff]);
    bf16x8 b0 = *reinterpret_cast<const bf16x8*>(&Bs[(wn + lrow) * AK + koff]);
    bf16x8 b1 = *reinterpret_cast<const bf16x8*>(&Bs[(wn + 16 + lrow) * AK + koff]);
    acc[0][0] = __builtin_amdgcn_mfma_f32_16x16x32_bf16(a0, b0, acc[0][0], 0, 0, 0);
    acc[0][1] = __builtin_amdgcn_mfma_f32_16x16x32_bf16(a0, b1, acc[0][1], 0, 0, 0);
    acc[1][0] = __builtin_amdgcn_mfma_f32_16x16x32_bf16(a1, b0, acc[1][0], 0, 0, 0);
    acc[1][1] = __builtin_amdgcn_mfma_f32_16x16x32_bf16(a1, b1, acc[1][1], 0, 0, 0);
  }

  #pragma unroll
  for (int mi = 0; mi < 2; ++mi)
    #pragma unroll
    for (int ni = 0; ni < 2; ++ni)
      #pragma unroll
      for (int r = 0; r < 4; ++r) {
        int tok = tok0 + wm + mi * 16 + quad * 4 + r;
        int n = n0 + wn + ni * 16 + lrow;
        float v = acc[mi][ni][r];
        if (EPI == 0) {
          v += bias[n];
          int bc = tok / TT, t = tok % TT;
          int tok2 = rev ? (bc * TT + (TT - 1 - t)) : tok;
          o0[(size_t)tok2 * 128 + n] = v;
        } else if (EPI == 1) {
          ob0[(size_t)tok * 512 + n] = f2b(v);
        } else if (EPI == 2) {
          if (n < 40) o0[(size_t)tok * 40 + n] = v;
        } else if (EPI == 3) {
          v += bias[n];
          o0[(size_t)tok * 128 + n] += v;
        }
      }
  (void)Nw;
}

// ---- merged weight prep: f32 -> bf16, transposed to [n][k] ----
// grid 1856: [0,1024) tin | [1024,1536) tout | [1536,1792) tx | [1792,1856) tsp
__global__ __launch_bounds__(256) void k_prep(const float* __restrict__ Win,
                                              const float* __restrict__ Wout,
                                              const float* __restrict__ Wx,
                                              const float* __restrict__ Wsp,
                                              u16* __restrict__ WTin,
                                              u16* __restrict__ WTout,
                                              u16* __restrict__ WTx,
                                              u16* __restrict__ WTsp) {
  int bid = blockIdx.x;
  int tid = threadIdx.x;
  if (bid < 1024) {
    int i = bid * 256 + tid;                 // 4*512*128
    int blk = i >> 16, r = i & 65535;
    int n = r >> 7, k = r & 127;
    WTin[i] = f2b(Win[blk * 65536 + k * 512 + n]);
  } else if (bid < 1536) {
    int i = (bid - 1024) * 256 + tid;        // 4*128*256
    int blk = i >> 15, r = i & 32767;
    int n = r >> 8, k = r & 255;
    WTout[i] = f2b(Wout[blk * 32768 + k * 128 + n]);
  } else if (bid < 1792) {
    int i = (bid - 1536) * 256 + tid;        // 4*64*256
    int blk = i >> 14, r = i & 16383;
    int n = r >> 8, k = r & 255;
    WTx[i] = (n < 40) ? f2b(Wx[blk * 10240 + k * 40 + n]) : 0;
  } else {
    int i = (bid - 1792) * 256 + tid;        // 128*128
    WTsp[i] = f2b(Wsp[i]);
  }
}

// spectral conv7 (pad 3) + bias + gelu -> F bf16 [token][c]
__global__ __launch_bounds__(256) void k_spec1(const float* __restrict__ x,
                                               const float* __restrict__ w1,
                                               const float* __restrict__ b1,
                                               u16* __restrict__ F) {
  __shared__ float xs[70];
  __shared__ float wsh[128 * 7];
  __shared__ float bs[128];
  int bc = blockIdx.x / 6, tile = blockIdx.x % 6;
  int tid = threadIdx.x;
  for (int i = tid; i < 896; i += 256) wsh[i] = w1[i];
  if (tid < 128) bs[tid] = b1[tid];
  int t0 = tile * 64;
  if (tid < 70) {
    int t = t0 - 3 + tid;
    xs[tid] = (t >= 0 && t < TT) ? x[(size_t)bc * TT + t] : 0.f;
  }
  __syncthreads();
  #pragma unroll
  for (int k = 0; k < 32; ++k) {
    int idx = tid + k * 256;
    int tl = idx >> 7, c = idx & 127;
    const float* wr = &wsh[c * 7];
    float acc = bs[c];
    #pragma unroll
    for (int j = 0; j < 7; ++j) acc += xs[tl + j] * wr[j];
    F[((size_t)(bc * TT + t0 + tl)) * 128 + c] = f2b(gelu_t(acc));
  }
}

// per-token LayerNorm over D=128: H f32 -> XLN bf16 (weights pre-offset)
__global__ __launch_bounds__(256) void k_ln(const float* __restrict__ H,
                                            const float* __restrict__ gg,
                                            const float* __restrict__ bb,
                                            u16* __restrict__ XLN) {
  int tid = threadIdx.x;
  int lane = tid & 63, wid = tid >> 6;
  int token = blockIdx.x * 4 + wid;
  const float* hr = H + (size_t)token * 128;
  float a = hr[lane], b = hr[lane + 64];
  float s = a + b;
  #pragma unroll
  for (int m = 32; m; m >>= 1) s += __shfl_xor(s, m);
  float mean = s * (1.f / 128.f);
  float d1 = a - mean, d2 = b - mean;
  float q = d1 * d1 + d2 * d2;
  #pragma unroll
  for (int m = 32; m; m >>= 1) q += __shfl_xor(q, m);
  float rs = rsqrtf(q * (1.f / 128.f) + 1e-5f);
  XLN[(size_t)token * 128 + lane] = f2b(d1 * rs * gg[lane] + bb[lane]);
  XLN[(size_t)token * 128 + lane + 64] =
      f2b(d2 * rs * gg[lane + 64] + bb[lane + 64]);
}

// causal depthwise conv (DC=4) + silu : XZ[:, :256] -> XC (4 chan/thread)
__global__ __launch_bounds__(256) void k_conv(const u16* __restrict__ XZ,
                                              const float* __restrict__ cw,
                                              const float* __restrict__ cb,
                                              u16* __restrict__ XC) {
  int idx = blockIdx.x * 256 + threadIdx.x;   // TOKn * 64
  int d4 = idx & 63;
  int tokg = idx >> 6;
  int t = tokg % TT;
  int dbase = d4 * 4;
  const float* cwp = cw + dbase * 4;
  float wv[4][4];
  #pragma unroll
  for (int j = 0; j < 4; ++j)
    #pragma unroll
    for (int k = 0; k < 4; ++k) wv[j][k] = cwp[j * 4 + k];
  float accv[4];
  #pragma unroll
  for (int j = 0; j < 4; ++j) accv[j] = cb[dbase + j];
  #pragma unroll
  for (int k = 0; k < 4; ++k) {
    int tt = t + k - 3;
    if (tt < 0) continue;
    ushort4 xv = *reinterpret_cast<const ushort4*>(
        &XZ[(size_t)(tokg + k - 3) * 512 + dbase]);
    u16 xa[4];
    *reinterpret_cast<ushort4*>(xa) = xv;
    #pragma unroll
    for (int j = 0; j < 4; ++j) accv[j] += b2f(xa[j]) * wv[j][k];
  }
  u16 oa[4];
  #pragma unroll
  for (int j = 0; j < 4; ++j) oa[j] = f2b(silu_f(accv[j]));
  *reinterpret_cast<ushort4*>(&XC[(size_t)tokg * 256 + dbase]) =
      *reinterpret_cast<ushort4*>(oa);
}

// ---------------------------------------------------------------------------
// selective scan v6d: grid = 128 bc x 4 dq, 256 threads.
// Scan phase: thread owns (d, 4 n): dl = tid>>2, ng = tid&3.
// dt phase once per d; zl staged; dtl/ybuf bf16 (LDS 42 KB -> 3 blocks/CU).
// ---------------------------------------------------------------------------
__global__ __launch_bounds__(256) void k_scan(
    const float* __restrict__ XDBL, u16* __restrict__ XC,
    const u16* __restrict__ XZ, const float* __restrict__ Wdt,
    const float* __restrict__ bdt, const float* __restrict__ Alog,
    const float* __restrict__ Dpv) {
  __shared__ float xdl[CH3 * 40];    // 10 KB
  __shared__ u16   dtl[CH3 * 64];    // 8 KB (bf16)
  __shared__ u16   xcl[CH3 * 64];    // 8 KB
  __shared__ u16   zl [CH3 * 64];    // 8 KB
  __shared__ u16   ybuf[CH3 * 64];   // 8 KB (bf16)
  const int tid = threadIdx.x;
  const int bc = blockIdx.x >> 2, dq = blockIdx.x & 3;
  const int ng = tid & 3;            // n-group (scan)
  const int dl = tid >> 2;           // d_local (scan)
  const int dcol = tid & 63;         // d_local (dt/epilogue)

  const int d_scan = dq * 64 + dl;
  float A[4];
  #pragma unroll
  for (int j = 0; j < 4; ++j)
    A[j] = -__expf(Alog[d_scan * 16 + ng * 4 + j]);
  float wdtr[8];
  #pragma unroll
  for (int j = 0; j < 8; ++j) wdtr[j] = Wdt[j * 256 + dq * 64 + dcol];
  const float bd = bdt[dq * 64 + dcol];
  const float dpar = Dpv[dq * 64 + dcol];

  const size_t base = (size_t)bc * TT;
  const float* xdg = XDBL + base * 40;
  const uint4* xcu4 = (const uint4*)XC;
  const uint4* zu4  = (const uint4*)XZ;

  float sx[10];
  uint4 scx[2], szx[2];
  auto issue_loads = [&](int c) {
    const float* p = xdg + (size_t)c * CH3 * 40;
    #pragma unroll
    for (int k = 0; k < 10; ++k) sx[k] = p[tid + k * 256];
    #pragma unroll
    for (int k = 0; k < 2; ++k) {
      int v = tid + k * 256;           // 0..511: t = v>>3, q = v&7
      int t = v >> 3, q = v & 7;
      size_t tok = base + (size_t)c * CH3 + t;
      scx[k] = xcu4[tok * 32 + dq * 8 + q];
      szx[k] = zu4[tok * 64 + 32 + dq * 8 + q];
    }
  };
  auto write_lds = [&]() {
    #pragma unroll
    for (int k = 0; k < 10; ++k) xdl[tid + k * 256] = sx[k];
    #pragma unroll
    for (int k = 0; k < 2; ++k) {
      int v = tid + k * 256;
      ((uint4*)xcl)[v] = scx[k];
      ((uint4*)zl)[v] = szx[k];
    }
  };

  issue_loads(0);
  write_lds();
  __syncthreads();

  float hc[4] = {};
  for (int c = 0; c < NCH3; ++c) {
    if (c + 1 < NCH3) issue_loads(c + 1);
    // dt phase: 16 values/thread at fixed dcol; float4 xdl reads
    #pragma unroll
    for (int k = 0; k < 16; ++k) {
      int t = (tid >> 6) + 4 * k;
      float4 x0 = *reinterpret_cast<const float4*>(&xdl[t * 40]);
      float4 x1 = *reinterpret_cast<const float4*>(&xdl[t * 40 + 4]);
      float acc = bd;
      acc += x0.x * wdtr[0] + x0.y * wdtr[1] + x0.z * wdtr[2] + x0.w * wdtr[3];
      acc += x1.x * wdtr[4] + x1.y * wdtr[5] + x1.z * wdtr[6] + x1.w * wdtr[7];
      dtl[t * 64 + dcol] = f2b(softplus_f(acc));
    }
    __syncthreads();
    // scan phase: 64 steps, 4 n per thread
    #pragma unroll 4
    for (int t = 0; t < CH3; ++t) {
      float dtv = b2f(dtl[t * 64 + dl]);
      float xcv = b2f(xcl[t * 64 + dl]);
      float4 Bv = *reinterpret_cast<const float4*>(&xdl[t * 40 + 8 + ng * 4]);
      float4 Cv = *reinterpret_cast<const float4*>(&xdl[t * 40 + 24 + ng * 4]);
      float dx = dtv * xcv;
      float e0 = __expf(A[0] * dtv);
      float e1 = __expf(A[1] * dtv);
      float e2 = __expf(A[2] * dtv);
      float e3 = __expf(A[3] * dtv);
      hc[0] = fmaf(hc[0], e0, dx * Bv.x);
      hc[1] = fmaf(hc[1], e1, dx * Bv.y);
      hc[2] = fmaf(hc[2], e2, dx * Bv.z);
      hc[3] = fmaf(hc[3], e3, dx * Bv.w);
      float yv = hc[0] * Cv.x + hc[1] * Cv.y + hc[2] * Cv.z + hc[3] * Cv.w;
      yv += __shfl_xor(yv, 1);
      yv += __shfl_xor(yv, 2);
      if (ng == 0) ybuf[t * 64 + dl] = f2b(yv);
    }
    __syncthreads();
    // epilogue: 16 values/thread at fixed dcol; coalesced store
    #pragma unroll
    for (int k = 0; k < 16; ++k) {
      int t = (tid >> 6) + 4 * k;
      int v = t * 64 + dcol;
      float y = b2f(ybuf[v]);
      float xcv = b2f(xcl[v]);
      float zz = b2f(zl[v]);
      y = (y + xcv * dpar) * silu_f(zz);
      XC[(base + (size_t)c * CH3 + t) * 256 + dq * 64 + dcol] = f2b(y);
    }
    __syncthreads();
    if (c + 1 < NCH3) {
      write_lds();
      __syncthreads();
    }
  }
}

// gather the 6 needed positions into XF[768][256] f32 (half=0 fwd,128 bwd)
__global__ __launch_bounds__(256) void k_gather(const float* __restrict__ H,
                                                float* __restrict__ XF,
                                                int half, int revpos) {
  int i = blockIdx.x * 256 + threadIdx.x;   // 768*128
  int col = i & 127, row = i >> 7;
  int bc = row / 6, u = row % 6;
  int tu = 63 + 64 * u;
  int t = revpos ? (TT - 1 - tu) : tu;
  XF[(size_t)row * 256 + half + col] = H[(size_t)(bc * TT + t) * 128 + col];
}

// fuse: FE[row][d] = XF[row][:] @ fuse_w + fuse_b   (768 rows, K=256)
__global__ __launch_bounds__(128) void k_fuse(const float* __restrict__ XF,
                                              const float* __restrict__ fw,
                                              const float* __restrict__ fb,
                                              float* __restrict__ FE) {
  int row = blockIdx.x;
  int d = threadIdx.x;
  __shared__ float rows[256];
  rows[d] = XF[(size_t)row * 256 + d];
  rows[128 + d] = XF[(size_t)row * 256 + 128 + d];
  __syncthreads();
  float acc = fb[d];
  for (int k = 0; k < 256; ++k) acc += rows[k] * fw[k * 128 + d];
  FE[(size_t)row * 128 + d] = acc;
}

// band projection + event reorder: TO[(bc*9+j)][d]
__global__ __launch_bounds__(128) void k_band(const float* __restrict__ FE,
                                              const float* __restrict__ pw,
                                              const float* __restrict__ pb,
                                              const float* __restrict__ pe,
                                              float* __restrict__ TO) {
  const int u_of[9] = {0, 1, 2, 2, 3, 4, 5, 5, 5};
  const int k_of[9] = {0, 0, 0, 1, 0, 0, 0, 1, 2};
  int bid = blockIdx.x;
  int bc = bid / 9, j = bid % 9;
  int u = u_of[j], kq = k_of[j];
  __shared__ float fs[128];
  int d = threadIdx.x;
  fs[d] = FE[(size_t)(bc * 6 + u) * 128 + d];
  __syncthreads();
  float acc = pb[kq * 128 + d] + pe[kq * 128 + d];
  const float* wp = pw + kq * 16384 + d;
  for (int c = 0; c < 128; ++c) acc += fs[c] * wp[c * 128];
  TO[(size_t)bid * 128 + d] = acc;
}

// depthwise 19x7 pos conv over (C=32, L=9) + residual -> T2 [b][c][l][d]
__global__ __launch_bounds__(256) void k_pos(const float* __restrict__ TO,
                                             const float* __restrict__ pw,
                                             const float* __restrict__ pb,
                                             float* __restrict__ T2) {
  int idx = blockIdx.x * 256 + threadIdx.x;   // 147456
  int d = idx & 127;
  int l = (idx >> 7) % 9;
  int c = (idx / 1152) & 31;
  int b = idx / 36864;
  float acc = 0.f;
  const float* wd = pw + d * 133;
  for (int i = 0; i < 19; ++i) {
    int ci = c + i - 9;
    if (ci < 0 || ci >= 32) continue;
    const float* trow = TO + (size_t)(b * 32 + ci) * 9 * 128 + d;
    #pragma unroll
    for (int jj = 0; jj < 7; ++jj) {
      int lj = l + jj - 3;
      if (lj < 0 || lj >= 9) continue;
      acc += trow[lj * 128] * wd[i * 7 + jj];
    }
  }
  T2[idx] = TO[idx] + acc + pb[d];
}

// hemisphere fusion: concat(own, permuted) @ hemi_w + hemi_b -> FL (flatf)
__global__ __launch_bounds__(128) void k_hemi(const float* __restrict__ T2,
                                              const int* __restrict__ perm,
                                              const float* __restrict__ hw,
                                              const float* __restrict__ hb,
                                              float* __restrict__ FL) {
  int bid = blockIdx.x;   // b*288 + c*9 + l
  int b = bid / 288;
  int c = (bid / 9) % 32;
  int l = bid % 9;
  int pc = perm[b * 32 + c];
  __shared__ float rows[256];
  int d = threadIdx.x;
  rows[d] = T2[((size_t)(b * 32 + c) * 9 + l) * 128 + d];
  rows[128 + d] = T2[((size_t)(b * 32 + pc) * 9 + l) * 128 + d];
  __syncthreads();
  float acc = hb[d];
  for (int k = 0; k < 256; ++k) acc += rows[k] * hw[k * 128 + d];
  FL[(size_t)(b * 32 + c) * 1152 + l * 128 + d] = acc;
}

// attention logits: LN(1152) -> @a_w1(200) -> gelu -> @a_w2 -> logit
__global__ __launch_bounds__(256) void k_attn(
    const float* __restrict__ FL, const float* __restrict__ lg,
    const float* __restrict__ lb, const float* __restrict__ w1,
    const float* __restrict__ b1, const float* __restrict__ w2,
    const float* __restrict__ ab2, float* __restrict__ LO) {
  __shared__ float xn[1152];
  __shared__ float sb[4];
  int row = blockIdx.x;
  int tid = threadIdx.x;
  const float* xr = FL + (size_t)row * 1152;
  float xl[5];
  int cnt = 0;
  float s = 0.f;
  for (int i = tid; i < 1152; i += 256) { xl[cnt] = xr[i]; s += xl[cnt]; ++cnt; }
  float tot = block_sum(s, sb);
  float mean = tot * (1.f / 1152.f);
  float q = 0.f;
  for (int k = 0; k < cnt; ++k) { float dd = xl[k] - mean; q += dd * dd; }
  float qt = block_sum(q, sb);
  float rs = rsqrtf(qt * (1.f / 1152.f) + 1e-5f);
  cnt = 0;
  for (int i = tid; i < 1152; i += 256) {
    xn[i] = (xl[cnt] - mean) * rs * lg[i] + lb[i];
    ++cnt;
  }
  __syncthreads();
  float g = 0.f;
  if (tid < 200) {
    float acc = b1[tid];
    for (int i = 0; i < 1152; ++i) acc += xn[i] * w1[i * 200 + tid];
    g = gelu_t(acc);
  }
  __syncthreads();
  if (tid < 200) xn[tid] = g;
  __syncthreads();
  float s2 = (tid < 200) ? xn[tid] * w2[tid] : 0.f;
  float t2 = block_sum(s2, sb);
  if (tid == 0) LO[row] = t2 + ab2[0];
}

// merged: softmax over C=32, weighted agg, final LN -> AGN[b][1152]
__global__ __launch_bounds__(256) void k_smln(const float* __restrict__ FL,
                                              const float* __restrict__ LO,
                                              const float* __restrict__ lg,
                                              const float* __restrict__ lb,
                                              float* __restrict__ AGN) {
  int b = blockIdx.x;
  int tid = threadIdx.x;
  __shared__ float w[32];
  __shared__ float sb[4];
  if (tid == 0) {
    float mx = -1e30f;
    for (int c = 0; c < 32; ++c) mx = fmaxf(mx, LO[b * 32 + c]);
    float sum = 0.f;
    for (int c = 0; c < 32; ++c) { float e = __expf(LO[b * 32 + c] - mx); w[c] = e; sum += e; }
    float inv = 1.f / sum;
    for (int c = 0; c < 32; ++c) w[c] *= inv;
  }
  __syncthreads();
  float xl[5];
  int cnt = 0;
  float s = 0.f;
  for (int f = tid; f < 1152; f += 256) {
    float acc = 0.f;
    for (int c = 0; c < 32; ++c) acc += FL[(size_t)(b * 32 + c) * 1152 + f] * w[c];
    xl[cnt++] = acc;
    s += acc;
  }
  float tot = block_sum(s, sb);
  float mean = tot * (1.f / 1152.f);
  float q = 0.f;
  for (int k = 0; k < cnt; ++k) { float dd = xl[k] - mean; q += dd * dd; }
  float qt = block_sum(q, sb);
  float rs = rsqrtf(qt * (1.f / 1152.f) + 1e-5f);
  cnt = 0;
  for (int f = tid; f < 1152; f += 256) {
    AGN[b * 1152 + f] = (xl[cnt] - mean) * rs * lg[f] + lb[f];
    ++cnt;
  }
}

// g1 = gelu(AGN @ m_w1 + m_b1), 1024 outs per b
__global__ __launch_bounds__(256) void k_g1(const float* __restrict__ AGN,
                                            const float* __restrict__ w1,
                                            const float* __restrict__ b1,
                                            float* __restrict__ G1) {
  int b = blockIdx.y;
  int j = blockIdx.x * 256 + threadIdx.x;   // 1024
  __shared__ float av[1152];
  for (int i = threadIdx.x; i < 1152; i += 256) av[i] = AGN[b * 1152 + i];
  __syncthreads();
  float acc = b1[j];
  for (int i = 0; i < 1152; ++i) acc += av[i] * w1[(size_t)i * 1024 + j];
  G1[b * 1024 + j] = gelu_t(acc);
}

// out = G1 @ m_w2 + m_b2 -> f32 d_out
__global__ __launch_bounds__(256) void k_f3(const float* __restrict__ G1,
                                            const float* __restrict__ w2,
                                            const float* __restrict__ b2v,
                                            float* __restrict__ out) {
  int b = blockIdx.y;
  int o = blockIdx.x * 256 + threadIdx.x;   // 768
  __shared__ float gv[1024];
  for (int i = threadIdx.x; i < 1024; i += 256) gv[i] = G1[b * 1024 + i];
  __syncthreads();
  float acc = b2v[o];
  for (int i = 0; i < 1024; ++i) acc += gv[i] * w2[(size_t)i * 768 + o];
  out[b * 768 + o] = acc;
}

extern "C" void kernel_launch(void* const* d_in, const int* in_sizes, int n_in,
                              void* d_out, int out_size, void* d_ws,
                              size_t ws_size, hipStream_t stream) {
  (void)in_sizes; (void)n_in; (void)out_size; (void)ws_size;
  const float* x      = (const float*)d_in[0];
  const int*   perm   = (const int*)d_in[1];
  const float* sp_w1  = (const float*)d_in[2];
  const float* sp_b1  = (const float*)d_in[3];
  const float* sp_w2  = (const float*)d_in[4];
  const float* sp_b2  = (const float*)d_in[5];
  const float* ln_g   = (const float*)d_in[6];
  const float* ln_b   = (const float*)d_in[7];
  const float* W_in   = (const float*)d_in[8];
  const float* conv_w = (const float*)d_in[9];
  const float* conv_b = (const float*)d_in[10];
  const float* W_x    = (const float*)d_in[11];
  const float* W_dt   = (const float*)d_in[12];
  const float* b_dt   = (const float*)d_in[13];
  const float* A_log  = (const float*)d_in[14];
  const float* Dp     = (const float*)d_in[15];
  const float* W_out  = (const float*)d_in[16];
  const float* b_out  = (const float*)d_in[17];
  const float* fuse_w = (const float*)d_in[18];
  const float* fuse_b = (const float*)d_in[19];
  const float* band_emb = (const float*)d_in[20];
  const float* band_pw  = (const float*)d_in[21];
  const float* band_pb  = (const float*)d_in[22];
  const float* pos_w  = (const float*)d_in[23];
  const float* pos_b  = (const float*)d_in[24];
  const float* hemi_w = (const float*)d_in[25];
  const float* hemi_b = (const float*)d_in[26];
  const float* a_ln_g = (const float*)d_in[27];
  const float* a_ln_b = (const float*)d_in[28];
  const float* a_w1   = (const float*)d_in[29];
  const float* a_b1   = (const float*)d_in[30];
  const float* a_w2   = (const float*)d_in[31];
  const float* a_b2   = (const float*)d_in[32];
  const float* m_ln_g = (const float*)d_in[33];
  const float* m_ln_b = (const float*)d_in[34];
  const float* m_w1   = (const float*)d_in[35];
  const float* m_b1   = (const float*)d_in[36];
  const float* m_w2   = (const float*)d_in[37];
  const float* m_b2   = (const float*)d_in[38];

  char* ws = (char*)d_ws;
  size_t off = 0;
  auto alloc = [&](size_t bytes) -> char* {
    char* p = ws + off;
    off += (bytes + 255) & ~(size_t)255;
    return p;
  };
  // peak ~139 MiB
  float* H    = (float*)alloc((size_t)TOKn * 128 * 4);   // 25.2M
  u16*   F    = (u16*)  alloc((size_t)TOKn * 128 * 2);   // 12.6M
  u16*   XLN  = (u16*)  alloc((size_t)TOKn * 128 * 2);   // 12.6M
  u16*   XZ   = (u16*)  alloc((size_t)TOKn * 512 * 2);   // 50.3M
  u16*   XC   = (u16*)  alloc((size_t)TOKn * 256 * 2);   // 25.2M
  float* XDBL = (float*)alloc((size_t)TOKn * 40 * 4);    // 7.9M
  u16*   WTin = (u16*)alloc(4 * 512 * 128 * 2);
  u16*   WTout= (u16*)alloc(4 * 128 * 256 * 2);
  u16*   WTx  = (u16*)alloc(4 * 64 * 256 * 2);
  u16*   WTsp = (u16*)alloc(128 * 128 * 2);
  float* XF   = (float*)alloc(768 * 256 * 4);
  float* FE   = (float*)alloc(768 * 128 * 4);
  float* TO   = (float*)alloc(1152 * 128 * 4);
  float* T2v  = (float*)alloc(147456 * 4);
  float* FL   = (float*)alloc(147456 * 4);
  float* LO   = (float*)alloc(128 * 4);
  float* AGN  = (float*)alloc(4 * 1152 * 4);
  float* G1v  = (float*)alloc(4 * 1024 * 4);

  // merged weight prep (bf16, [n][k])
  k_prep<<<dim3(1856), dim3(256), 0, stream>>>(
      W_in, W_out, W_x, sp_w2, WTin, WTout, WTx, WTsp);

  // spectral front-end
  k_spec1<<<dim3(BCn * 6), dim3(256), 0, stream>>>(x, sp_w1, sp_b1, F);

  auto mamba_round = [&](int blk) {
    k_ln<<<dim3(TOKn / 4), dim3(256), 0, stream>>>(
        H, ln_g + blk * 128, ln_b + blk * 128, XLN);
    k_mm<1, 128><<<dim3(TOKn / 64, 8), dim3(256), 0, stream>>>(
        XLN, WTin + (size_t)blk * 65536, nullptr, 512, 0, nullptr, XZ);
    k_conv<<<dim3(TOKn * 64 / 256), dim3(256), 0, stream>>>(
        XZ, conv_w + blk * 1024, conv_b + blk * 256, XC);
    k_mm<2, 256><<<dim3(TOKn / 64, 1), dim3(256), 0, stream>>>(
        XC, WTx + (size_t)blk * 16384, nullptr, 40, 0, XDBL, nullptr);
    k_scan<<<dim3(BCn * 4), dim3(256), 0, stream>>>(
        XDBL, XC, XZ, W_dt + blk * 2048, b_dt + blk * 256,
        A_log + blk * 4096, Dp + blk * 256);
    k_mm<3, 256><<<dim3(TOKn / 64, 2), dim3(256), 0, stream>>>(
        XC, WTout + (size_t)blk * 32768, b_out + blk * 128, 128, 0,
        H, nullptr);
  };

  // forward chain (blocks 0,1)
  k_mm<0, 128><<<dim3(TOKn / 64, 2), dim3(256), 0, stream>>>(
      F, WTsp, sp_b2, 128, 0, H, nullptr);
  mamba_round(0);
  mamba_round(1);
  k_gather<<<dim3(384), dim3(256), 0, stream>>>(H, XF, 0, 0);

  // backward chain (blocks 2,3) on time-reversed h
  k_mm<0, 128><<<dim3(TOKn / 64, 2), dim3(256), 0, stream>>>(
      F, WTsp, sp_b2, 128, 1, H, nullptr);
  mamba_round(2);
  mamba_round(3);
  k_gather<<<dim3(384), dim3(256), 0, stream>>>(H, XF, 128, 1);

  // tail
  k_fuse<<<dim3(768), dim3(128), 0, stream>>>(XF, fuse_w, fuse_b, FE);
  k_band<<<dim3(1152), dim3(128), 0, stream>>>(FE, band_pw, band_pb, band_emb, TO);
  k_pos<<<dim3(576), dim3(256), 0, stream>>>(TO, pos_w, pos_b, T2v);
  k_hemi<<<dim3(1152), dim3(128), 0, stream>>>(T2v, perm, hemi_w, hemi_b, FL);
  k_attn<<<dim3(128), dim3(256), 0, stream>>>(FL, a_ln_g, a_ln_b, a_w1, a_b1,
                                              a_w2, a_b2, LO);
  k_smln<<<dim3(4), dim3(256), 0, stream>>>(FL, LO, m_ln_g, m_ln_b, AGN);
  k_g1<<<dim3(4, 4), dim3(256), 0, stream>>>(AGN, m_w1, m_b1, G1v);
  k_f3<<<dim3(3, 4), dim3(256), 0, stream>>>(G1v, m_w2, m_b2, (float*)d_out);
}

// Round 15
// 1302.074 us; speedup vs baseline: 1.1358x; 1.0087x over previous
//
#include <hip/hip_runtime.h>

// ---------------------------------------------------------------------------
// CSBrainAlign: spectral conv -> 4 mamba blocks (fwd chain then bwd chain,
// sequential) -> fuse@6 positions -> band/pos/hemi -> attn pool -> MLP.
// EXTERNAL dtype: float32 (per reference), int32 perm. Internal acts bf16,
// residual H fp32, fuse path fp32, output fp32.
// R6: scan lane=(d,n) remap. R7: GEMM family -> MFMA bf16.
// R9 scan v6 (best 164us). R10: mm XCD grids, LDS spec1. R13: k_prep/k_smln.
// R14: k_gf reverted to k_g1+k_f3.
// R15: scan v7 — 512-thread blocks, 2 states/thread (16 waves/CU, 2x
//      latency hiding; grid-size was the occupancy limit, not LDS);
//      LN fused into W_in GEMM (k_mm1ln) — removes 4 k_ln launches and
//      the XLN round-trip.
// ---------------------------------------------------------------------------

typedef unsigned short u16;
using bf16x8 = __attribute__((ext_vector_type(8))) short;
using f32x4  = __attribute__((ext_vector_type(4))) float;

#define TT    384      // sequence length N*P
#define BCn   128      // B*C
#define TOKn  49152    // BCn*TT (one chain)
#define CH3   64       // scan chunk (steps)
#define NCH3  (TT/CH3) // 6 chunks

__device__ __forceinline__ float b2f(u16 u) {
  return __uint_as_float(((unsigned)u) << 16);
}
__device__ __forceinline__ u16 f2b(float f) {
  unsigned u = __float_as_uint(f);
  u += 0x7fffu + ((u >> 16) & 1u);   // RNE
  return (u16)(u >> 16);
}
__device__ __forceinline__ float gelu_t(float x) {
  float u2 = 1.5957691216057308f * (x + 0.044715f * x * x * x);
  float e = __expf(u2);
  float th = 1.f - 2.f / (e + 1.f);
  return 0.5f * x * (1.f + th);
}
__device__ __forceinline__ float silu_f(float x) { return x / (1.f + __expf(-x)); }
__device__ __forceinline__ float softplus_f(float x) {
  return fmaxf(x, 0.f) + log1pf(__expf(-fabsf(x)));
}

__device__ __forceinline__ float block_sum(float v, float* sb) {
  #pragma unroll
  for (int m = 32; m; m >>= 1) v += __shfl_xor(v, m);
  int lane = threadIdx.x & 63, wid = threadIdx.x >> 6;
  if (lane == 0) sb[wid] = v;
  __syncthreads();
  float tot = sb[0] + sb[1] + sb[2] + sb[3];
  __syncthreads();
  return tot;
}

// ---------------------------------------------------------------------------
// MFMA GEMM: out[tok][n] = X[tok][0:KT] @ W[0:KT][n],  X bf16, WT bf16 [n][k].
// grid = (tokTiles, nTiles): same-A blocks land on one XCD.
// EPI: 0 spectral -> H f32 (+bias; rev!=0 time-reversed)
//      2 W_x      -> XDBL f32 (stride 40, store n<40)
//      3 W_out    -> H += acc + bias
// ---------------------------------------------------------------------------
template <int EPI, int KT>
__global__ __launch_bounds__(256) void k_mm(
    const u16* __restrict__ X, const u16* __restrict__ WT,
    const float* __restrict__ bias, int Nw, int rev,
    float* __restrict__ o0, u16* __restrict__ ob0) {
  constexpr int AK = KT + 8;          // row pad
  __shared__ u16 As[64 * AK];
  __shared__ u16 Bs[64 * AK];
  const int tid = threadIdx.x;
  const int tok0 = blockIdx.x * 64;
  const int n0 = blockIdx.y * 64;

  constexpr int VPR = KT / 8;
  constexpr int ITER = 64 * VPR / 256;
  #pragma unroll
  for (int j = 0; j < ITER; ++j) {
    int idx = tid + j * 256;
    int row = idx / VPR, vec = idx % VPR;
    *reinterpret_cast<uint4*>(&As[row * AK + vec * 8]) =
        *reinterpret_cast<const uint4*>(&X[(size_t)(tok0 + row) * KT + vec * 8]);
    *reinterpret_cast<uint4*>(&Bs[row * AK + vec * 8]) =
        *reinterpret_cast<const uint4*>(&WT[(size_t)(n0 + row) * KT + vec * 8]);
  }
  __syncthreads();

  const int w = tid >> 6, lane = tid & 63;
  const int wm = (w & 1) * 32, wn = (w >> 1) * 32;
  const int lrow = lane & 15, quad = lane >> 4;
  f32x4 acc[2][2] = {};
  #pragma unroll
  for (int ks = 0; ks < KT / 32; ++ks) {
    int koff = ks * 32 + quad * 8;
    bf16x8 a0 = *reinterpret_cast<const bf16x8*>(&As[(wm + lrow) * AK + koff]);
    bf16x8 a1 = *reinterpret_cast<const bf16x8*>(&As[(wm + 16 + lrow) * AK + koff]);
    bf16x8 b0 = *reinterpret_cast<const bf16x8*>(&Bs[(wn + lrow) * AK + koff]);
    bf16x8 b1 = *reinterpret_cast<const bf16x8*>(&Bs[(wn + 16 + lrow) * AK + koff]);
    acc[0][0] = __builtin_amdgcn_mfma_f32_16x16x32_bf16(a0, b0, acc[0][0], 0, 0, 0);
    acc[0][1] = __builtin_amdgcn_mfma_f32_16x16x32_bf16(a0, b1, acc[0][1], 0, 0, 0);
    acc[1][0] = __builtin_amdgcn_mfma_f32_16x16x32_bf16(a1, b0, acc[1][0], 0, 0, 0);
    acc[1][1] = __builtin_amdgcn_mfma_f32_16x16x32_bf16(a1, b1, acc[1][1], 0, 0, 0);
  }

  #pragma unroll
  for (int mi = 0; mi < 2; ++mi)
    #pragma unroll
    for (int ni = 0; ni < 2; ++ni)
      #pragma unroll
      for (int r = 0; r < 4; ++r) {
        int tok = tok0 + wm + mi * 16 + quad * 4 + r;
        int n = n0 + wn + ni * 16 + lrow;
        float v = acc[mi][ni][r];
        if (EPI == 0) {
          v += bias[n];
          int bc = tok / TT, t = tok % TT;
          int tok2 = rev ? (bc * TT + (TT - 1 - t)) : tok;
          o0[(size_t)tok2 * 128 + n] = v;
        } else if (EPI == 2) {
          if (n < 40) o0[(size_t)tok * 40 + n] = v;
        } else if (EPI == 3) {
          v += bias[n];
          o0[(size_t)tok * 128 + n] += v;
        }
      }
  (void)Nw; (void)ob0;
}

// W_in GEMM with fused LayerNorm on the A path: XZ = LN(H) @ W_in (bf16 out).
__global__ __launch_bounds__(256) void k_mm1ln(
    const float* __restrict__ H, const u16* __restrict__ WT,
    const float* __restrict__ gg, const float* __restrict__ bb,
    u16* __restrict__ XZ) {
  constexpr int KT = 128, AK = KT + 8;
  __shared__ u16 As[64 * AK];
  __shared__ u16 Bs[64 * AK];
  __shared__ float gs[128], bs[128];
  const int tid = threadIdx.x;
  const int tok0 = blockIdx.x * 64;
  const int n0 = blockIdx.y * 64;
  if (tid < 128) gs[tid] = gg[tid];
  else bs[tid - 128] = bb[tid - 128];
  // B staging: 64 rows x 16 uint4
  #pragma unroll
  for (int j = 0; j < 4; ++j) {
    int idx = tid + j * 256;
    int row = idx >> 4, vec = idx & 15;
    *reinterpret_cast<uint4*>(&Bs[row * AK + vec * 8]) =
        *reinterpret_cast<const uint4*>(&WT[(size_t)(n0 + row) * KT + vec * 8]);
  }
  // A staging with LN: 4 threads per row (shfl groups stay in-wave)
  {
    int row = tid >> 2, part = tid & 3;
    const float* hr = H + (size_t)(tok0 + row) * 128 + part * 32;
    float v[32];
    float s = 0.f;
    #pragma unroll
    for (int i = 0; i < 8; ++i) {
      float4 f = *reinterpret_cast<const float4*>(hr + i * 4);
      v[i * 4 + 0] = f.x; v[i * 4 + 1] = f.y;
      v[i * 4 + 2] = f.z; v[i * 4 + 3] = f.w;
      s += f.x + f.y + f.z + f.w;
    }
    s += __shfl_xor(s, 1);
    s += __shfl_xor(s, 2);
    float mean = s * (1.f / 128.f);
    float q = 0.f;
    #pragma unroll
    for (int i = 0; i < 32; ++i) { float d = v[i] - mean; q += d * d; }
    q += __shfl_xor(q, 1);
    q += __shfl_xor(q, 2);
    float rs = rsqrtf(q * (1.f / 128.f) + 1e-5f);
    __syncthreads();           // gs/bs ready (all threads reach here)
    #pragma unroll
    for (int i = 0; i < 32; ++i) {
      int c = part * 32 + i;
      As[row * AK + c] = f2b((v[i] - mean) * rs * gs[c] + bs[c]);
    }
  }
  __syncthreads();

  const int w = tid >> 6, lane = tid & 63;
  const int wm = (w & 1) * 32, wn = (w >> 1) * 32;
  const int lrow = lane & 15, quad = lane >> 4;
  f32x4 acc[2][2] = {};
  #pragma unroll
  for (int ks = 0; ks < KT / 32; ++ks) {
    int koff = ks * 32 + quad * 8;
    bf16x8 a0 = *reinterpret_cast<const bf16x8*>(&As[(wm + lrow) * AK + koff]);
    bf16x8 a1 = *reinterpret_cast<const bf16x8*>(&As[(wm + 16 + lrow) * AK + koff]);
    bf16x8 b0 = *reinterpret_cast<const bf16x8*>(&Bs[(wn + lrow) * AK + koff]);
    bf16x8 b1 = *reinterpret_cast<const bf16x8*>(&Bs[(wn + 16 + lrow) * AK + koff]);
    acc[0][0] = __builtin_amdgcn_mfma_f32_16x16x32_bf16(a0, b0, acc[0][0], 0, 0, 0);
    acc[0][1] = __builtin_amdgcn_mfma_f32_16x16x32_bf16(a0, b1, acc[0][1], 0, 0, 0);
    acc[1][0] = __builtin_amdgcn_mfma_f32_16x16x32_bf16(a1, b0, acc[1][0], 0, 0, 0);
    acc[1][1] = __builtin_amdgcn_mfma_f32_16x16x32_bf16(a1, b1, acc[1][1], 0, 0, 0);
  }
  #pragma unroll
  for (int mi = 0; mi < 2; ++mi)
    #pragma unroll
    for (int ni = 0; ni < 2; ++ni)
      #pragma unroll
      for (int r = 0; r < 4; ++r) {
        int tok = tok0 + wm + mi * 16 + quad * 4 + r;
        int n = n0 + wn + ni * 16 + lrow;
        XZ[(size_t)tok * 512 + n] = f2b(acc[mi][ni][r]);
      }
}

// ---- merged weight prep: f32 -> bf16, transposed to [n][k] ----
__global__ __launch_bounds__(256) void k_prep(const float* __restrict__ Win,
                                              const float* __restrict__ Wout,
                                              const float* __restrict__ Wx,
                                              const float* __restrict__ Wsp,
                                              u16* __restrict__ WTin,
                                              u16* __restrict__ WTout,
                                              u16* __restrict__ WTx,
                                              u16* __restrict__ WTsp) {
  int bid = blockIdx.x;
  int tid = threadIdx.x;
  if (bid < 1024) {
    int i = bid * 256 + tid;                 // 4*512*128
    int blk = i >> 16, r = i & 65535;
    int n = r >> 7, k = r & 127;
    WTin[i] = f2b(Win[blk * 65536 + k * 512 + n]);
  } else if (bid < 1536) {
    int i = (bid - 1024) * 256 + tid;        // 4*128*256
    int blk = i >> 15, r = i & 32767;
    int n = r >> 8, k = r & 255;
    WTout[i] = f2b(Wout[blk * 32768 + k * 128 + n]);
  } else if (bid < 1792) {
    int i = (bid - 1536) * 256 + tid;        // 4*64*256
    int blk = i >> 14, r = i & 16383;
    int n = r >> 8, k = r & 255;
    WTx[i] = (n < 40) ? f2b(Wx[blk * 10240 + k * 40 + n]) : 0;
  } else {
    int i = (bid - 1792) * 256 + tid;        // 128*128
    WTsp[i] = f2b(Wsp[i]);
  }
}

// spectral conv7 (pad 3) + bias + gelu -> F bf16 [token][c]
__global__ __launch_bounds__(256) void k_spec1(const float* __restrict__ x,
                                               const float* __restrict__ w1,
                                               const float* __restrict__ b1,
                                               u16* __restrict__ F) {
  __shared__ float xs[70];
  __shared__ float wsh[128 * 7];
  __shared__ float bs[128];
  int bc = blockIdx.x / 6, tile = blockIdx.x % 6;
  int tid = threadIdx.x;
  for (int i = tid; i < 896; i += 256) wsh[i] = w1[i];
  if (tid < 128) bs[tid] = b1[tid];
  int t0 = tile * 64;
  if (tid < 70) {
    int t = t0 - 3 + tid;
    xs[tid] = (t >= 0 && t < TT) ? x[(size_t)bc * TT + t] : 0.f;
  }
  __syncthreads();
  #pragma unroll
  for (int k = 0; k < 32; ++k) {
    int idx = tid + k * 256;
    int tl = idx >> 7, c = idx & 127;
    const float* wr = &wsh[c * 7];
    float acc = bs[c];
    #pragma unroll
    for (int j = 0; j < 7; ++j) acc += xs[tl + j] * wr[j];
    F[((size_t)(bc * TT + t0 + tl)) * 128 + c] = f2b(gelu_t(acc));
  }
}

// causal depthwise conv (DC=4) + silu : XZ[:, :256] -> XC (4 chan/thread)
__global__ __launch_bounds__(256) void k_conv(const u16* __restrict__ XZ,
                                              const float* __restrict__ cw,
                                              const float* __restrict__ cb,
                                              u16* __restrict__ XC) {
  int idx = blockIdx.x * 256 + threadIdx.x;   // TOKn * 64
  int d4 = idx & 63;
  int tokg = idx >> 6;
  int t = tokg % TT;
  int dbase = d4 * 4;
  const float* cwp = cw + dbase * 4;
  float wv[4][4];
  #pragma unroll
  for (int j = 0; j < 4; ++j)
    #pragma unroll
    for (int k = 0; k < 4; ++k) wv[j][k] = cwp[j * 4 + k];
  float accv[4];
  #pragma unroll
  for (int j = 0; j < 4; ++j) accv[j] = cb[dbase + j];
  #pragma unroll
  for (int k = 0; k < 4; ++k) {
    int tt = t + k - 3;
    if (tt < 0) continue;
    ushort4 xv = *reinterpret_cast<const ushort4*>(
        &XZ[(size_t)(tokg + k - 3) * 512 + dbase]);
    u16 xa[4];
    *reinterpret_cast<ushort4*>(xa) = xv;
    #pragma unroll
    for (int j = 0; j < 4; ++j) accv[j] += b2f(xa[j]) * wv[j][k];
  }
  u16 oa[4];
  #pragma unroll
  for (int j = 0; j < 4; ++j) oa[j] = f2b(silu_f(accv[j]));
  *reinterpret_cast<ushort4*>(&XC[(size_t)tokg * 256 + dbase]) =
      *reinterpret_cast<ushort4*>(oa);
}

// ---------------------------------------------------------------------------
// selective scan v7: grid = 128 bc x 4 dq, 512 threads (8 waves/block,
// 16 waves/CU). Thread owns (d, 2 n): dl = tid>>3, ng = tid&7.
// dt phase once per d; zl staged; dtl/ybuf bf16.
// ---------------------------------------------------------------------------
__global__ __launch_bounds__(512) void k_scan(
    const float* __restrict__ XDBL, u16* __restrict__ XC,
    const u16* __restrict__ XZ, const float* __restrict__ Wdt,
    const float* __restrict__ bdt, const float* __restrict__ Alog,
    const float* __restrict__ Dpv) {
  __shared__ float xdl[CH3 * 40];    // 10 KB
  __shared__ u16   dtl[CH3 * 64];    // 8 KB (bf16)
  __shared__ u16   xcl[CH3 * 64];    // 8 KB
  __shared__ u16   zl [CH3 * 64];    // 8 KB
  __shared__ u16   ybuf[CH3 * 64];   // 8 KB (bf16)
  const int tid = threadIdx.x;
  const int bc = blockIdx.x >> 2, dq = blockIdx.x & 3;
  const int ng = tid & 7;            // n-group (scan): n = 2ng, 2ng+1
  const int dl = tid >> 3;           // d_local (scan)
  const int dcol = tid & 63;         // d_local (dt/epilogue)
  const int trow = tid >> 6;         // 0..7 (dt/epilogue)

  const int d_scan = dq * 64 + dl;
  float A[2];
  #pragma unroll
  for (int j = 0; j < 2; ++j)
    A[j] = -__expf(Alog[d_scan * 16 + ng * 2 + j]);
  float wdtr[8];
  #pragma unroll
  for (int j = 0; j < 8; ++j) wdtr[j] = Wdt[j * 256 + dq * 64 + dcol];
  const float bd = bdt[dq * 64 + dcol];
  const float dpar = Dpv[dq * 64 + dcol];

  const size_t base = (size_t)bc * TT;
  const float* xdg = XDBL + base * 40;
  const uint4* xcu4 = (const uint4*)XC;
  const uint4* zu4  = (const uint4*)XZ;

  float sx[5];
  uint4 scx, szx;
  auto issue_loads = [&](int c) {
    const float* p = xdg + (size_t)c * CH3 * 40;
    #pragma unroll
    for (int k = 0; k < 5; ++k) sx[k] = p[tid + k * 512];
    int t = tid >> 3, q = tid & 7;
    size_t tok = base + (size_t)c * CH3 + t;
    scx = xcu4[tok * 32 + dq * 8 + q];
    szx = zu4[tok * 64 + 32 + dq * 8 + q];
  };
  auto write_lds = [&]() {
    #pragma unroll
    for (int k = 0; k < 5; ++k) xdl[tid + k * 512] = sx[k];
    ((uint4*)xcl)[tid] = scx;
    ((uint4*)zl)[tid] = szx;
  };

  issue_loads(0);
  write_lds();
  __syncthreads();

  float hc[2] = {};
  for (int c = 0; c < NCH3; ++c) {
    if (c + 1 < NCH3) issue_loads(c + 1);
    // dt phase: 8 values/thread at fixed dcol; float4 xdl reads
    #pragma unroll
    for (int k = 0; k < 8; ++k) {
      int t = trow + 8 * k;
      float4 x0 = *reinterpret_cast<const float4*>(&xdl[t * 40]);
      float4 x1 = *reinterpret_cast<const float4*>(&xdl[t * 40 + 4]);
      float acc = bd;
      acc += x0.x * wdtr[0] + x0.y * wdtr[1] + x0.z * wdtr[2] + x0.w * wdtr[3];
      acc += x1.x * wdtr[4] + x1.y * wdtr[5] + x1.z * wdtr[6] + x1.w * wdtr[7];
      dtl[t * 64 + dcol] = f2b(softplus_f(acc));
    }
    __syncthreads();
    // scan phase: 64 steps, 2 n per thread
    #pragma unroll 4
    for (int t = 0; t < CH3; ++t) {
      float dtv = b2f(dtl[t * 64 + dl]);
      float xcv = b2f(xcl[t * 64 + dl]);
      float2 Bv = *reinterpret_cast<const float2*>(&xdl[t * 40 + 8 + ng * 2]);
      float2 Cv = *reinterpret_cast<const float2*>(&xdl[t * 40 + 24 + ng * 2]);
      float dx = dtv * xcv;
      float e0 = __expf(A[0] * dtv);
      float e1 = __expf(A[1] * dtv);
      hc[0] = fmaf(hc[0], e0, dx * Bv.x);
      hc[1] = fmaf(hc[1], e1, dx * Bv.y);
      float yv = hc[0] * Cv.x + hc[1] * Cv.y;
      yv += __shfl_xor(yv, 1);
      yv += __shfl_xor(yv, 2);
      yv += __shfl_xor(yv, 4);
      if (ng == 0) ybuf[t * 64 + dl] = f2b(yv);
    }
    __syncthreads();
    // epilogue: 8 values/thread at fixed dcol; coalesced store
    #pragma unroll
    for (int k = 0; k < 8; ++k) {
      int t = trow + 8 * k;
      int v = t * 64 + dcol;
      float y = b2f(ybuf[v]);
      float xcv = b2f(xcl[v]);
      float zz = b2f(zl[v]);
      y = (y + xcv * dpar) * silu_f(zz);
      XC[(base + (size_t)c * CH3 + t) * 256 + dq * 64 + dcol] = f2b(y);
    }
    __syncthreads();
    if (c + 1 < NCH3) {
      write_lds();
      __syncthreads();
    }
  }
}

// gather the 6 needed positions into XF[768][256] f32 (half=0 fwd,128 bwd)
__global__ __launch_bounds__(256) void k_gather(const float* __restrict__ H,
                                                float* __restrict__ XF,
                                                int half, int revpos) {
  int i = blockIdx.x * 256 + threadIdx.x;   // 768*128
  int col = i & 127, row = i >> 7;
  int bc = row / 6, u = row % 6;
  int tu = 63 + 64 * u;
  int t = revpos ? (TT - 1 - tu) : tu;
  XF[(size_t)row * 256 + half + col] = H[(size_t)(bc * TT + t) * 128 + col];
}

// fuse: FE[row][d] = XF[row][:] @ fuse_w + fuse_b   (768 rows, K=256)
__global__ __launch_bounds__(128) void k_fuse(const float* __restrict__ XF,
                                              const float* __restrict__ fw,
                                              const float* __restrict__ fb,
                                              float* __restrict__ FE) {
  int row = blockIdx.x;
  int d = threadIdx.x;
  __shared__ float rows[256];
  rows[d] = XF[(size_t)row * 256 + d];
  rows[128 + d] = XF[(size_t)row * 256 + 128 + d];
  __syncthreads();
  float acc = fb[d];
  for (int k = 0; k < 256; ++k) acc += rows[k] * fw[k * 128 + d];
  FE[(size_t)row * 128 + d] = acc;
}

// band projection + event reorder: TO[(bc*9+j)][d]
__global__ __launch_bounds__(128) void k_band(const float* __restrict__ FE,
                                              const float* __restrict__ pw,
                                              const float* __restrict__ pb,
                                              const float* __restrict__ pe,
                                              float* __restrict__ TO) {
  const int u_of[9] = {0, 1, 2, 2, 3, 4, 5, 5, 5};
  const int k_of[9] = {0, 0, 0, 1, 0, 0, 0, 1, 2};
  int bid = blockIdx.x;
  int bc = bid / 9, j = bid % 9;
  int u = u_of[j], kq = k_of[j];
  __shared__ float fs[128];
  int d = threadIdx.x;
  fs[d] = FE[(size_t)(bc * 6 + u) * 128 + d];
  __syncthreads();
  float acc = pb[kq * 128 + d] + pe[kq * 128 + d];
  const float* wp = pw + kq * 16384 + d;
  for (int c = 0; c < 128; ++c) acc += fs[c] * wp[c * 128];
  TO[(size_t)bid * 128 + d] = acc;
}

// depthwise 19x7 pos conv over (C=32, L=9) + residual -> T2 [b][c][l][d]
__global__ __launch_bounds__(256) void k_pos(const float* __restrict__ TO,
                                             const float* __restrict__ pw,
                                             const float* __restrict__ pb,
                                             float* __restrict__ T2) {
  int idx = blockIdx.x * 256 + threadIdx.x;   // 147456
  int d = idx & 127;
  int l = (idx >> 7) % 9;
  int c = (idx / 1152) & 31;
  int b = idx / 36864;
  float acc = 0.f;
  const float* wd = pw + d * 133;
  for (int i = 0; i < 19; ++i) {
    int ci = c + i - 9;
    if (ci < 0 || ci >= 32) continue;
    const float* trow = TO + (size_t)(b * 32 + ci) * 9 * 128 + d;
    #pragma unroll
    for (int jj = 0; jj < 7; ++jj) {
      int lj = l + jj - 3;
      if (lj < 0 || lj >= 9) continue;
      acc += trow[lj * 128] * wd[i * 7 + jj];
    }
  }
  T2[idx] = TO[idx] + acc + pb[d];
}

// hemisphere fusion: concat(own, permuted) @ hemi_w + hemi_b -> FL (flatf)
__global__ __launch_bounds__(128) void k_hemi(const float* __restrict__ T2,
                                              const int* __restrict__ perm,
                                              const float* __restrict__ hw,
                                              const float* __restrict__ hb,
                                              float* __restrict__ FL) {
  int bid = blockIdx.x;   // b*288 + c*9 + l
  int b = bid / 288;
  int c = (bid / 9) % 32;
  int l = bid % 9;
  int pc = perm[b * 32 + c];
  __shared__ float rows[256];
  int d = threadIdx.x;
  rows[d] = T2[((size_t)(b * 32 + c) * 9 + l) * 128 + d];
  rows[128 + d] = T2[((size_t)(b * 32 + pc) * 9 + l) * 128 + d];
  __syncthreads();
  float acc = hb[d];
  for (int k = 0; k < 256; ++k) acc += rows[k] * hw[k * 128 + d];
  FL[(size_t)(b * 32 + c) * 1152 + l * 128 + d] = acc;
}

// attention logits: LN(1152) -> @a_w1(200) -> gelu -> @a_w2 -> logit
__global__ __launch_bounds__(256) void k_attn(
    const float* __restrict__ FL, const float* __restrict__ lg,
    const float* __restrict__ lb, const float* __restrict__ w1,
    const float* __restrict__ b1, const float* __restrict__ w2,
    const float* __restrict__ ab2, float* __restrict__ LO) {
  __shared__ float xn[1152];
  __shared__ float sb[4];
  int row = blockIdx.x;
  int tid = threadIdx.x;
  const float* xr = FL + (size_t)row * 1152;
  float xl[5];
  int cnt = 0;
  float s = 0.f;
  for (int i = tid; i < 1152; i += 256) { xl[cnt] = xr[i]; s += xl[cnt]; ++cnt; }
  float tot = block_sum(s, sb);
  float mean = tot * (1.f / 1152.f);
  float q = 0.f;
  for (int k = 0; k < cnt; ++k) { float dd = xl[k] - mean; q += dd * dd; }
  float qt = block_sum(q, sb);
  float rs = rsqrtf(qt * (1.f / 1152.f) + 1e-5f);
  cnt = 0;
  for (int i = tid; i < 1152; i += 256) {
    xn[i] = (xl[cnt] - mean) * rs * lg[i] + lb[i];
    ++cnt;
  }
  __syncthreads();
  float g = 0.f;
  if (tid < 200) {
    float acc = b1[tid];
    for (int i = 0; i < 1152; ++i) acc += xn[i] * w1[i * 200 + tid];
    g = gelu_t(acc);
  }
  __syncthreads();
  if (tid < 200) xn[tid] = g;
  __syncthreads();
  float s2 = (tid < 200) ? xn[tid] * w2[tid] : 0.f;
  float t2 = block_sum(s2, sb);
  if (tid == 0) LO[row] = t2 + ab2[0];
}

// merged: softmax over C=32, weighted agg, final LN -> AGN[b][1152]
__global__ __launch_bounds__(256) void k_smln(const float* __restrict__ FL,
                                              const float* __restrict__ LO,
                                              const float* __restrict__ lg,
                                              const float* __restrict__ lb,
                                              float* __restrict__ AGN) {
  int b = blockIdx.x;
  int tid = threadIdx.x;
  __shared__ float w[32];
  __shared__ float sb[4];
  if (tid == 0) {
    float mx = -1e30f;
    for (int c = 0; c < 32; ++c) mx = fmaxf(mx, LO[b * 32 + c]);
    float sum = 0.f;
    for (int c = 0; c < 32; ++c) { float e = __expf(LO[b * 32 + c] - mx); w[c] = e; sum += e; }
    float inv = 1.f / sum;
    for (int c = 0; c < 32; ++c) w[c] *= inv;
  }
  __syncthreads();
  float xl[5];
  int cnt = 0;
  float s = 0.f;
  for (int f = tid; f < 1152; f += 256) {
    float acc = 0.f;
    for (int c = 0; c < 32; ++c) acc += FL[(size_t)(b * 32 + c) * 1152 + f] * w[c];
    xl[cnt++] = acc;
    s += acc;
  }
  float tot = block_sum(s, sb);
  float mean = tot * (1.f / 1152.f);
  float q = 0.f;
  for (int k = 0; k < cnt; ++k) { float dd = xl[k] - mean; q += dd * dd; }
  float qt = block_sum(q, sb);
  float rs = rsqrtf(qt * (1.f / 1152.f) + 1e-5f);
  cnt = 0;
  for (int f = tid; f < 1152; f += 256) {
    AGN[b * 1152 + f] = (xl[cnt] - mean) * rs * lg[f] + lb[f];
    ++cnt;
  }
}

// g1 = gelu(AGN @ m_w1 + m_b1), 1024 outs per b
__global__ __launch_bounds__(256) void k_g1(const float* __restrict__ AGN,
                                            const float* __restrict__ w1,
                                            const float* __restrict__ b1,
                                            float* __restrict__ G1) {
  int b = blockIdx.y;
  int j = blockIdx.x * 256 + threadIdx.x;   // 1024
  __shared__ float av[1152];
  for (int i = threadIdx.x; i < 1152; i += 256) av[i] = AGN[b * 1152 + i];
  __syncthreads();
  float acc = b1[j];
  for (int i = 0; i < 1152; ++i) acc += av[i] * w1[(size_t)i * 1024 + j];
  G1[b * 1024 + j] = gelu_t(acc);
}

// out = G1 @ m_w2 + m_b2 -> f32 d_out
__global__ __launch_bounds__(256) void k_f3(const float* __restrict__ G1,
                                            const float* __restrict__ w2,
                                            const float* __restrict__ b2v,
                                            float* __restrict__ out) {
  int b = blockIdx.y;
  int o = blockIdx.x * 256 + threadIdx.x;   // 768
  __shared__ float gv[1024];
  for (int i = threadIdx.x; i < 1024; i += 256) gv[i] = G1[b * 1024 + i];
  __syncthreads();
  float acc = b2v[o];
  for (int i = 0; i < 1024; ++i) acc += gv[i] * w2[(size_t)i * 768 + o];
  out[b * 768 + o] = acc;
}

extern "C" void kernel_launch(void* const* d_in, const int* in_sizes, int n_in,
                              void* d_out, int out_size, void* d_ws,
                              size_t ws_size, hipStream_t stream) {
  (void)in_sizes; (void)n_in; (void)out_size; (void)ws_size;
  const float* x      = (const float*)d_in[0];
  const int*   perm   = (const int*)d_in[1];
  const float* sp_w1  = (const float*)d_in[2];
  const float* sp_b1  = (const float*)d_in[3];
  const float* sp_w2  = (const float*)d_in[4];
  const float* sp_b2  = (const float*)d_in[5];
  const float* ln_g   = (const float*)d_in[6];
  const float* ln_b   = (const float*)d_in[7];
  const float* W_in   = (const float*)d_in[8];
  const float* conv_w = (const float*)d_in[9];
  const float* conv_b = (const float*)d_in[10];
  const float* W_x    = (const float*)d_in[11];
  const float* W_dt   = (const float*)d_in[12];
  const float* b_dt   = (const float*)d_in[13];
  const float* A_log  = (const float*)d_in[14];
  const float* Dp     = (const float*)d_in[15];
  const float* W_out  = (const float*)d_in[16];
  const float* b_out  = (const float*)d_in[17];
  const float* fuse_w = (const float*)d_in[18];
  const float* fuse_b = (const float*)d_in[19];
  const float* band_emb = (const float*)d_in[20];
  const float* band_pw  = (const float*)d_in[21];
  const float* band_pb  = (const float*)d_in[22];
  const float* pos_w  = (const float*)d_in[23];
  const float* pos_b  = (const float*)d_in[24];
  const float* hemi_w = (const float*)d_in[25];
  const float* hemi_b = (const float*)d_in[26];
  const float* a_ln_g = (const float*)d_in[27];
  const float* a_ln_b = (const float*)d_in[28];
  const float* a_w1   = (const float*)d_in[29];
  const float* a_b1   = (const float*)d_in[30];
  const float* a_w2   = (const float*)d_in[31];
  const float* a_b2   = (const float*)d_in[32];
  const float* m_ln_g = (const float*)d_in[33];
  const float* m_ln_b = (const float*)d_in[34];
  const float* m_w1   = (const float*)d_in[35];
  const float* m_b1   = (const float*)d_in[36];
  const float* m_w2   = (const float*)d_in[37];
  const float* m_b2   = (const float*)d_in[38];

  char* ws = (char*)d_ws;
  size_t off = 0;
  auto alloc = [&](size_t bytes) -> char* {
    char* p = ws + off;
    off += (bytes + 255) & ~(size_t)255;
    return p;
  };
  // peak ~126 MiB (XLN removed)
  float* H    = (float*)alloc((size_t)TOKn * 128 * 4);   // 25.2M
  u16*   F    = (u16*)  alloc((size_t)TOKn * 128 * 2);   // 12.6M
  u16*   XZ   = (u16*)  alloc((size_t)TOKn * 512 * 2);   // 50.3M
  u16*   XC   = (u16*)  alloc((size_t)TOKn * 256 * 2);   // 25.2M
  float* XDBL = (float*)alloc((size_t)TOKn * 40 * 4);    // 7.9M
  u16*   WTin = (u16*)alloc(4 * 512 * 128 * 2);
  u16*   WTout= (u16*)alloc(4 * 128 * 256 * 2);
  u16*   WTx  = (u16*)alloc(4 * 64 * 256 * 2);
  u16*   WTsp = (u16*)alloc(128 * 128 * 2);
  float* XF   = (float*)alloc(768 * 256 * 4);
  float* FE   = (float*)alloc(768 * 128 * 4);
  float* TO   = (float*)alloc(1152 * 128 * 4);
  float* T2v  = (float*)alloc(147456 * 4);
  float* FL   = (float*)alloc(147456 * 4);
  float* LO   = (float*)alloc(128 * 4);
  float* AGN  = (float*)alloc(4 * 1152 * 4);
  float* G1v  = (float*)alloc(4 * 1024 * 4);

  // merged weight prep (bf16, [n][k])
  k_prep<<<dim3(1856), dim3(256), 0, stream>>>(
      W_in, W_out, W_x, sp_w2, WTin, WTout, WTx, WTsp);

  // spectral front-end
  k_spec1<<<dim3(BCn * 6), dim3(256), 0, stream>>>(x, sp_w1, sp_b1, F);

  auto mamba_round = [&](int blk) {
    k_mm1ln<<<dim3(TOKn / 64, 8), dim3(256), 0, stream>>>(
        H, WTin + (size_t)blk * 65536, ln_g + blk * 128, ln_b + blk * 128, XZ);
    k_conv<<<dim3(TOKn * 64 / 256), dim3(256), 0, stream>>>(
        XZ, conv_w + blk * 1024, conv_b + blk * 256, XC);
    k_mm<2, 256><<<dim3(TOKn / 64, 1), dim3(256), 0, stream>>>(
        XC, WTx + (size_t)blk * 16384, nullptr, 40, 0, XDBL, nullptr);
    k_scan<<<dim3(BCn * 4), dim3(512), 0, stream>>>(
        XDBL, XC, XZ, W_dt + blk * 2048, b_dt + blk * 256,
        A_log + blk * 4096, Dp + blk * 256);
    k_mm<3, 256><<<dim3(TOKn / 64, 2), dim3(256), 0, stream>>>(
        XC, WTout + (size_t)blk * 32768, b_out + blk * 128, 128, 0,
        H, nullptr);
  };

  // forward chain (blocks 0,1)
  k_mm<0, 128><<<dim3(TOKn / 64, 2), dim3(256), 0, stream>>>(
      F, WTsp, sp_b2, 128, 0, H, nullptr);
  mamba_round(0);
  mamba_round(1);
  k_gather<<<dim3(384), dim3(256), 0, stream>>>(H, XF, 0, 0);

  // backward chain (blocks 2,3) on time-reversed h
  k_mm<0, 128><<<dim3(TOKn / 64, 2), dim3(256), 0, stream>>>(
      F, WTsp, sp_b2, 128, 1, H, nullptr);
  mamba_round(2);
  mamba_round(3);
  k_gather<<<dim3(384), dim3(256), 0, stream>>>(H, XF, 128, 1);

  // tail
  k_fuse<<<dim3(768), dim3(128), 0, stream>>>(XF, fuse_w, fuse_b, FE);
  k_band<<<dim3(1152), dim3(128), 0, stream>>>(FE, band_pw, band_pb, band_emb, TO);
  k_pos<<<dim3(576), dim3(256), 0, stream>>>(TO, pos_w, pos_b, T2v);
  k_hemi<<<dim3(1152), dim3(128), 0, stream>>>(T2v, perm, hemi_w, hemi_b, FL);
  k_attn<<<dim3(128), dim3(256), 0, stream>>>(FL, a_ln_g, a_ln_b, a_w1, a_b1,
                                              a_w2, a_b2, LO);
  k_smln<<<dim3(4), dim3(256), 0, stream>>>(FL, LO, m_ln_g, m_ln_b, AGN);
  k_g1<<<dim3(4, 4), dim3(256), 0, stream>>>(AGN, m_w1, m_b1, G1v);
  k_f3<<<dim3(3, 4), dim3(256), 0, stream>>>(G1v, m_w2, m_b2, (float*)d_out);
}